// Round 1
// baseline (378.866 us; speedup 1.0000x reference)
//
#include <hip/hip_runtime.h>

// B=32, S=577, D=768, H=12, Dh=64. fp32 in/out, bf16 MFMA compute.
#define NB 32
#define SEQ 577
#define SP 640      // padded seq (5*128, 10*64)
#define DM 768
#define NH 12
#define DH 64
#define NC 10       // key chunks of 64

typedef __attribute__((ext_vector_type(8))) short bf16x8;   // K=32 MFMA A/B frag
typedef __attribute__((ext_vector_type(4))) short bf16x4;   // K=16 MFMA A/B frag
typedef __attribute__((ext_vector_type(4))) float f32x4;
typedef __attribute__((ext_vector_type(2))) unsigned int u32x2;
typedef __attribute__((ext_vector_type(4))) unsigned int u32x4;
typedef unsigned short u16;

__device__ __forceinline__ u16 f2bf(float f) {  // RNE float->bf16
  unsigned int u = __builtin_bit_cast(unsigned int, f);
  u += 0x7fffu + ((u >> 16) & 1u);
  return (u16)(u >> 16);
}

// pack two fp32 -> bf16 pair (round-half-up) in one v_perm
__device__ __forceinline__ unsigned int pack_bf2(float a, float b) {
  unsigned int ua = __builtin_bit_cast(unsigned int, a) + 0x8000u;
  unsigned int ub = __builtin_bit_cast(unsigned int, b) + 0x8000u;
  return __builtin_amdgcn_perm(ub, ua, 0x07060302u);  // lo16=bf(a), hi16=bf(b)
}

__device__ __forceinline__ void g2l16(const void* g, void* lds) {
  __builtin_amdgcn_global_load_lds(
      (const __attribute__((address_space(1))) void*)g,
      (__attribute__((address_space(3))) void*)lds, 16, 0, 0);
}

// ---- kernel 1: fp32 -> bf16 cast of hidden_states -------------------------
__global__ void cvt_x_kernel(const float* __restrict__ X, u16* __restrict__ Xb, int n4) {
  int i = blockIdx.x * 256 + threadIdx.x;
  if (i >= n4) return;
  f32x4 v = *reinterpret_cast<const f32x4*>(X + (size_t)i * 4);
  u32x2 p;
  p[0] = (unsigned)f2bf(v[0]) | ((unsigned)f2bf(v[1]) << 16);
  p[1] = (unsigned)f2bf(v[2]) | ((unsigned)f2bf(v[3]) << 16);
  *reinterpret_cast<u32x2*>(Xb + (size_t)i * 4) = p;
}

// ---- kernel 2: cast + transpose weights: Wt[qkv][n][k] --------------------
__global__ void cvt_w_kernel(const float* __restrict__ Wq, const float* __restrict__ Wk,
                             const float* __restrict__ Wv, u16* __restrict__ Wt) {
  int idx = blockIdx.x * 256 + threadIdx.x;
  int m = blockIdx.y;
  const float* W = (m == 0) ? Wq : (m == 1) ? Wk : Wv;
  int k = idx / DM, n = idx - k * DM;
  Wt[(size_t)m * DM * DM + (size_t)n * DM + k] = f2bf(W[idx]);
}

// ---- kernel 3: fused QKV GEMM (bf16 MFMA, 128x128 tile, BK=32) ------------
// v2: 2-phase double-buffered pipeline with counted vmcnt (T3/T4-lite).
// Next K-step's global_load_lds issued before consuming current buffer;
// s_waitcnt vmcnt(4) keeps the 4 prefetch loads in flight across the
// barrier (never drain to 0 in the main loop). Buffer-release barrier sits
// right after the ds_reads so MFMAs overlap the next stage issue.
__global__ __launch_bounds__(256, 3)
void qkv_gemm_kernel(const u16* __restrict__ Xb, const u16* __restrict__ Wt,
                     const float* __restrict__ bq, const float* __restrict__ bk,
                     const float* __restrict__ bv,
                     u16* __restrict__ Qw, u16* __restrict__ Kw, u16* __restrict__ Vw) {
  __shared__ alignas(16) u16 As[2][128 * 32];
  __shared__ alignas(16) u16 Bs[2][128 * 32];

  const int tid = threadIdx.x;
  const int lane = tid & 63;
  const int wid = tid >> 6;
  const int wr = wid >> 1, wc = wid & 1;
  const int l15 = lane & 15, lq = lane >> 4;

  const int mt = blockIdx.x;
  const int nt = blockIdx.y;
  const int qkv = blockIdx.z;

  const int b = mt / 5;
  const int t0 = (mt - b * 5) * 128;
  const int n0 = nt * 128;

  const u16* Wm = Wt + (size_t)qkv * DM * DM;
  const float* bias = (qkv == 0) ? bq : (qkv == 1) ? bk : bv;

  int tA0 = t0 + wid * 16 + l15;
  int tA1 = t0 + (wid + 4) * 16 + l15;
  int xr0 = b * SEQ + (tA0 < SEQ ? tA0 : SEQ - 1);
  int xr1 = b * SEQ + (tA1 < SEQ ? tA1 : SEQ - 1);
  const u16* gA0 = Xb + (size_t)xr0 * DM + lq * 8;
  const u16* gA1 = Xb + (size_t)xr1 * DM + lq * 8;
  const u16* gB0 = Wm + (size_t)(n0 + wid * 16 + l15) * DM + lq * 8;
  const u16* gB1 = Wm + (size_t)(n0 + (wid + 4) * 16 + l15) * DM + lq * 8;

  f32x4 acc[4][4];
#pragma unroll
  for (int i = 0; i < 4; ++i)
#pragma unroll
    for (int j = 0; j < 4; ++j)
#pragma unroll
      for (int r = 0; r < 4; ++r) acc[i][j][r] = 0.0f;

  auto stage = [&](int buf, int k0) {
    g2l16(gA0 + k0, &As[buf][wid * 512]);
    g2l16(gA1 + k0, &As[buf][(wid + 4) * 512]);
    g2l16(gB0 + k0, &Bs[buf][wid * 512]);
    g2l16(gB1 + k0, &Bs[buf][(wid + 4) * 512]);
  };

  // prologue: stage K-step 0 into buffer 0 (stays in flight; counted wait below)
  stage(0, 0);

  const int NT = DM / 32;  // 24
  for (int t = 0; t < NT; ++t) {
    const int cur = t & 1;
    if (t + 1 < NT) {
      stage(cur ^ 1, (t + 1) * 32);  // prefetch next K-step (4 more vm ops)
      asm volatile("s_waitcnt vmcnt(4)" ::: "memory");  // own buf[cur] loads done
    } else {
      asm volatile("s_waitcnt vmcnt(0)" ::: "memory");
    }
    __builtin_amdgcn_s_barrier();  // all waves' buf[cur] loads landed

    bf16x8 af[4], bfq[4];
#pragma unroll
    for (int i = 0; i < 4; ++i)
      af[i] = *reinterpret_cast<const bf16x8*>(&As[cur][((wr * 4 + i) * 64 + lane) * 8]);
#pragma unroll
    for (int j = 0; j < 4; ++j)
      bfq[j] = *reinterpret_cast<const bf16x8*>(&Bs[cur][((wc * 4 + j) * 64 + lane) * 8]);

    asm volatile("s_waitcnt lgkmcnt(0)" ::: "memory");  // frags in regs
    __builtin_amdgcn_s_barrier();  // buf[cur] free for overwrite next iter

#pragma unroll
    for (int i = 0; i < 4; ++i)
#pragma unroll
      for (int j = 0; j < 4; ++j)
        acc[i][j] = __builtin_amdgcn_mfma_f32_16x16x32_bf16(af[i], bfq[j], acc[i][j], 0, 0, 0);
  }

  const float sfold = 0.18033688011112042f;  // (1/sqrt(64)) * log2(e)
#pragma unroll
  for (int j = 0; j < 4; ++j) {
    int col = n0 + wc * 64 + j * 16 + l15;
    int h = col >> 6;
    int d = col & 63;
    float bb = bias[col];
#pragma unroll
    for (int i = 0; i < 4; ++i) {
      int trow = t0 + wr * 64 + i * 16 + lq * 4;
      if (qkv == 2) {
        float v0 = acc[i][j][0] + bb, v1 = acc[i][j][1] + bb;
        float v2 = acc[i][j][2] + bb, v3 = acc[i][j][3] + bb;
        u32x2 p;
        p[0] = (unsigned)f2bf(v0) | ((unsigned)f2bf(v1) << 16);
        p[1] = (unsigned)f2bf(v2) | ((unsigned)f2bf(v3) << 16);
        size_t o = ((size_t)(b * NH + h) * DH + d) * SP + trow;
        *reinterpret_cast<u32x2*>(Vw + o) = p;
      } else {
        u16* dst = ((qkv == 0) ? Qw : Kw) + ((size_t)(b * NH + h) * SP + trow) * DH + d;
#pragma unroll
        for (int r = 0; r < 4; ++r) {
          float v = acc[i][j][r] + bb;
          if (qkv == 0) v *= sfold;
          dst[r * DH] = f2bf(v);
        }
      }
    }
  }
}

// ---- kernel 4: flash attention v3 -----------------------------------------
// Block = 4 waves = 128 queries (wave owns 32 = 2 q-tiles of 16).
// Per 64-key chunk: K staged via global_load_lds (fragment-ordered 16B/lane),
// V staged via VGPR->ds_write (fragment-ordered 8B/lane), double-buffered,
// one barrier per chunk (m97 structure). S^T = K·Q^T keeps softmax in-lane;
// P stays in-lane as the K=16 PV B-frag (O^T = Vt·P^T). Zero shuffles.
#if __has_builtin(__builtin_amdgcn_mfma_f32_16x16x16bf16_1k)
#define MFMA16(a, b, c) __builtin_amdgcn_mfma_f32_16x16x16bf16_1k(a, b, c, 0, 0, 0)
#define HAVE_MFMA16 1
#elif __has_builtin(__builtin_amdgcn_mfma_f32_16x16x16_bf16)
#define MFMA16(a, b, c) __builtin_amdgcn_mfma_f32_16x16x16_bf16(a, b, c, 0, 0, 0)
#define HAVE_MFMA16 1
#else
#define HAVE_MFMA16 0
#endif

__global__ __launch_bounds__(256)
void attn_kernel(const u16* __restrict__ Qw, const u16* __restrict__ Kw,
                 const u16* __restrict__ Vw, float* __restrict__ out) {
  // Kc: 8 entries (t,half) x 64 lanes x 16B = 8KB per buffer
  // Vc: 16 entries (dt,t)  x 64 lanes x  8B = 8KB per buffer
  __shared__ alignas(16) u16 Kc[2][8 * 64 * 8];
  __shared__ alignas(16) u16 Vc[2][16 * 64 * 4];

  const int tid = threadIdx.x;
  const int lane = tid & 63;
  const int wid = tid >> 6;
  const int l15 = lane & 15, lq = lane >> 4;
  const int bh = blockIdx.y;
  const int b = bh / NH;
  const int h = bh - b * NH;
  const int q0 = blockIdx.x * 128 + wid * 32;  // wave: queries q0..q0+31

  const u16* Qb = Qw + (size_t)bh * SP * DH;
  const u16* Kb = Kw + (size_t)bh * SP * DH;
  const u16* Vb = Vw + (size_t)bh * DH * SP;

  // Q B-frags: [qt][half], B[n=q=l15][k=half*32+lq*8+j]
  bf16x8 qf[2][2];
#pragma unroll
  for (int qt = 0; qt < 2; ++qt)
#pragma unroll
    for (int hf = 0; hf < 2; ++hf)
      qf[qt][hf] = *reinterpret_cast<const bf16x8*>(
          &Qb[(q0 + qt * 16 + l15) * DH + hf * 32 + lq * 8]);

  // staging source addresses (chunk-invariant parts)
  // K: wave stages entries e=2*wid+half: K[c0+wid*16+l15][half*32+lq*8..+8]
  const u16* gK = Kb + (size_t)(wid * 16 + l15) * DH + lq * 8;
  // V: wave stages entries e=4*wid+t: Vt[wid*16+l15][c0+t*16+lq*4..+4]
  const u16* gV = Vb + (size_t)(wid * 16 + l15) * SP + lq * 4;

  float mrow[2] = {-__builtin_inff(), -__builtin_inff()};
  float lrow[2] = {0.0f, 0.0f};
  f32x4 acc[2][4];  // [qt][dt]; d = dt*16+lq*4+r, q = q0+qt*16+l15
#pragma unroll
  for (int qt = 0; qt < 2; ++qt)
#pragma unroll
    for (int dt = 0; dt < 4; ++dt)
#pragma unroll
      for (int r = 0; r < 4; ++r) acc[qt][dt][r] = 0.0f;

  // ---- prologue: stage chunk 0 into buffer 0 ----
  g2l16(gK, &Kc[0][(wid * 2 + 0) * 512]);
  g2l16(gK + 32, &Kc[0][(wid * 2 + 1) * 512]);
  {
    u32x2 v[4];
#pragma unroll
    for (int t = 0; t < 4; ++t)
      v[t] = *reinterpret_cast<const u32x2*>(gV + t * 16);
#pragma unroll
    for (int t = 0; t < 4; ++t)
      *reinterpret_cast<u32x2*>(&Vc[0][((wid * 4 + t) * 64 + lane) * 4]) = v[t];
  }
  __syncthreads();

  for (int c = 0; c < NC; ++c) {
    const int cur = c & 1;
    const int c0 = c * 64;
    // ---- prefetch chunk c+1 (async; drained by end-of-loop barrier) ----
    u32x2 vn[4];
    if (c + 1 < NC) {
      const u16* gKn = gK + (size_t)(c0 + 64) * DH;
      g2l16(gKn, &Kc[cur ^ 1][(wid * 2 + 0) * 512]);
      g2l16(gKn + 32, &Kc[cur ^ 1][(wid * 2 + 1) * 512]);
#pragma unroll
      for (int t = 0; t < 4; ++t)
        vn[t] = *reinterpret_cast<const u32x2*>(gV + (c0 + 64) + t * 16);
    }

    // ---- S^T = K·Q^T from LDS K ----
    f32x4 s[2][4];
#pragma unroll
    for (int t = 0; t < 4; ++t) {
      bf16x8 kf0 = *reinterpret_cast<const bf16x8*>(&Kc[cur][((t * 2 + 0) * 64 + lane) * 8]);
      bf16x8 kf1 = *reinterpret_cast<const bf16x8*>(&Kc[cur][((t * 2 + 1) * 64 + lane) * 8]);
#pragma unroll
      for (int qt = 0; qt < 2; ++qt) {
        f32x4 z;
#pragma unroll
        for (int r = 0; r < 4; ++r) z[r] = 0.0f;
        z = __builtin_amdgcn_mfma_f32_16x16x32_bf16(kf0, qf[qt][0], z, 0, 0, 0);
        z = __builtin_amdgcn_mfma_f32_16x16x32_bf16(kf1, qf[qt][1], z, 0, 0, 0);
        s[qt][t] = z;
      }
    }
    // ---- mask padded keys (uniform branch, last chunk only) ----
    if (c0 + 64 > SEQ) {
#pragma unroll
      for (int qt = 0; qt < 2; ++qt)
#pragma unroll
        for (int t = 0; t < 4; ++t)
#pragma unroll
          for (int r = 0; r < 4; ++r) {
            int key = c0 + t * 16 + lq * 4 + r;
            s[qt][t][r] = (key < SEQ) ? s[qt][t][r] : -__builtin_inff();
          }
    }
    // ---- online softmax (in-lane over 16 + shfl 16,32) ----
    float alpha[2];
    unsigned int pku[2][4][2];
#pragma unroll
    for (int qt = 0; qt < 2; ++qt) {
      float mx = s[qt][0][0];
#pragma unroll
      for (int t = 0; t < 4; ++t)
#pragma unroll
        for (int r = 0; r < 4; ++r) mx = fmaxf(mx, s[qt][t][r]);
      mx = fmaxf(mx, __shfl_xor(mx, 16));
      mx = fmaxf(mx, __shfl_xor(mx, 32));
      float mn = fmaxf(mrow[qt], mx);
      alpha[qt] = __builtin_amdgcn_exp2f(mrow[qt] - mn);
      mrow[qt] = mn;
      float sm = 0.0f;
#pragma unroll
      for (int t = 0; t < 4; ++t) {
        float p0 = __builtin_amdgcn_exp2f(s[qt][t][0] - mn);
        float p1 = __builtin_amdgcn_exp2f(s[qt][t][1] - mn);
        float p2 = __builtin_amdgcn_exp2f(s[qt][t][2] - mn);
        float p3 = __builtin_amdgcn_exp2f(s[qt][t][3] - mn);
        sm += (p0 + p1) + (p2 + p3);
        pku[qt][t][0] = pack_bf2(p0, p1);
        pku[qt][t][1] = pack_bf2(p2, p3);
      }
      sm += __shfl_xor(sm, 16);
      sm += __shfl_xor(sm, 32);
      lrow[qt] = lrow[qt] * alpha[qt] + sm;
    }

#if HAVE_MFMA16
    // ---- PV: O^T = Vt·P^T (K=16 MFMA; vf shared across q-tiles) ----
#pragma unroll
    for (int dt = 0; dt < 4; ++dt) {
      bf16x4 vf[4];
#pragma unroll
      for (int t = 0; t < 4; ++t)
        vf[t] = *reinterpret_cast<const bf16x4*>(&Vc[cur][((dt * 4 + t) * 64 + lane) * 4]);
#pragma unroll
      for (int qt = 0; qt < 2; ++qt) {
        f32x4 a = acc[qt][dt];
#pragma unroll
        for (int r = 0; r < 4; ++r) a[r] *= alpha[qt];
#pragma unroll
        for (int t = 0; t < 4; ++t) {
          bf16x4 pf = __builtin_bit_cast(bf16x4, u32x2{pku[qt][t][0], pku[qt][t][1]});
          a = MFMA16(vf[t], pf, a);
        }
        acc[qt][dt] = a;
      }
    }
#else
    // ---- fallback: K=32 MFMA, B-frag via bpermute (v2-verified pattern) ----
#pragma unroll
    for (int qt = 0; qt < 2; ++qt) {
      unsigned int bfrag[2][4];
#pragma unroll
      for (int hh = 0; hh < 2; ++hh)
#pragma unroll
        for (int w = 0; w < 4; ++w) {
          int srcl = l15 + 16 * (2 * (lq & 1) + (w >> 1));
          unsigned int lo = (unsigned int)__shfl((int)pku[qt][2 * hh][w & 1], srcl);
          unsigned int hi = (unsigned int)__shfl((int)pku[qt][2 * hh + 1][w & 1], srcl);
          bfrag[hh][w] = (lq < 2) ? lo : hi;
        }
#pragma unroll
      for (int dt = 0; dt < 4; ++dt) {
        f32x4 a = acc[qt][dt];
#pragma unroll
        for (int r = 0; r < 4; ++r) a[r] *= alpha[qt];
#pragma unroll
        for (int hh = 0; hh < 2; ++hh) {
          u32x2 w0 = *reinterpret_cast<const u32x2*>(&Vc[cur][((dt * 4 + 2 * hh) * 64 + lane) * 4]);
          u32x2 w1 = *reinterpret_cast<const u32x2*>(&Vc[cur][((dt * 4 + 2 * hh + 1) * 64 + lane) * 4]);
          u32x4 vw = {w0[0], w0[1], w1[0], w1[1]};
          u32x4 pw = {bfrag[hh][0], bfrag[hh][1], bfrag[hh][2], bfrag[hh][3]};
          a = __builtin_amdgcn_mfma_f32_16x16x32_bf16(
              __builtin_bit_cast(bf16x8, vw), __builtin_bit_cast(bf16x8, pw), a, 0, 0, 0);
        }
        acc[qt][dt] = a;
      }
    }
#endif

    // ---- write prefetched V into the other buffer, then barrier ----
    if (c + 1 < NC) {
#pragma unroll
      for (int t = 0; t < 4; ++t)
        *reinterpret_cast<u32x2*>(&Vc[cur ^ 1][((wid * 4 + t) * 64 + lane) * 4]) = vn[t];
    }
    __syncthreads();
  }

  // ---- epilogue: direct stores (lane holds 4 consecutive d -> 16B store) ----
#pragma unroll
  for (int qt = 0; qt < 2; ++qt) {
    int q = q0 + qt * 16 + l15;
    if (q < SEQ) {
      float rl = 1.0f / lrow[qt];
      float* orow = out + ((size_t)b * SEQ + q) * DM + h * DH;
#pragma unroll
      for (int dt = 0; dt < 4; ++dt) {
        f32x4 v = acc[qt][dt];
#pragma unroll
        for (int r = 0; r < 4; ++r) v[r] *= rl;
        *reinterpret_cast<f32x4*>(&orow[dt * 16 + lq * 4]) = v;
      }
    }
  }
}

extern "C" void kernel_launch(void* const* d_in, const int* in_sizes, int n_in,
                              void* d_out, int out_size, void* d_ws, size_t ws_size,
                              hipStream_t stream) {
  (void)in_sizes; (void)n_in; (void)out_size; (void)ws_size;
  const float* X  = (const float*)d_in[0];
  const float* Wq = (const float*)d_in[1];
  const float* bq = (const float*)d_in[2];
  const float* Wk = (const float*)d_in[3];
  const float* bk = (const float*)d_in[4];
  const float* Wv = (const float*)d_in[5];
  const float* bv = (const float*)d_in[6];
  float* out = (float*)d_out;

  char* ws = (char*)d_ws;
  u16* Xb = (u16*)ws;
  u16* Wt = (u16*)(ws + 28366848);
  u16* Qw = (u16*)(ws + 28366848 + 3538944);
  u16* Kw = Qw + (size_t)NB * NH * SP * DH;
  u16* Vw = Kw + (size_t)NB * NH * SP * DH;

  cvt_x_kernel<<<dim3(13848), 256, 0, stream>>>(X, Xb, 3545088);
  cvt_w_kernel<<<dim3(2304, 3), 256, 0, stream>>>(Wq, Wk, Wv, Wt);
  qkv_gemm_kernel<<<dim3(160, 6, 3), 256, 0, stream>>>(Xb, Wt, bq, bk, bv, Qw, Kw, Vw);
  attn_kernel<<<dim3(5, NB * NH), 256, 0, stream>>>(Qw, Kw, Vw, out);
}

// Round 2
// 363.986 us; speedup vs baseline: 1.0409x; 1.0409x over previous
//
#include <hip/hip_runtime.h>

// B=32, S=577, D=768, H=12, Dh=64. fp32 in/out, bf16 MFMA compute.
#define NB 32
#define SEQ 577
#define SP 640      // padded seq (5*128, 10*64)
#define DM 768
#define NH 12
#define DH 64
#define NC 10       // key chunks of 64

typedef __attribute__((ext_vector_type(8))) short bf16x8;   // K=32 MFMA A/B frag
typedef __attribute__((ext_vector_type(4))) short bf16x4;   // K=16 MFMA A/B frag
typedef __attribute__((ext_vector_type(4))) float f32x4;
typedef __attribute__((ext_vector_type(2))) unsigned int u32x2;
typedef __attribute__((ext_vector_type(4))) unsigned int u32x4;
typedef unsigned short u16;

__device__ __forceinline__ u16 f2bf(float f) {  // RNE float->bf16
  unsigned int u = __builtin_bit_cast(unsigned int, f);
  u += 0x7fffu + ((u >> 16) & 1u);
  return (u16)(u >> 16);
}

// pack two fp32 -> bf16 pair (round-half-up) in one v_perm
__device__ __forceinline__ unsigned int pack_bf2(float a, float b) {
  unsigned int ua = __builtin_bit_cast(unsigned int, a) + 0x8000u;
  unsigned int ub = __builtin_bit_cast(unsigned int, b) + 0x8000u;
  return __builtin_amdgcn_perm(ub, ua, 0x07060302u);  // lo16=bf(a), hi16=bf(b)
}

__device__ __forceinline__ void g2l16(const void* g, void* lds) {
  __builtin_amdgcn_global_load_lds(
      (const __attribute__((address_space(1))) void*)g,
      (__attribute__((address_space(3))) void*)lds, 16, 0, 0);
}

// ---- kernel 1: fp32 -> bf16 cast of hidden_states -------------------------
__global__ void cvt_x_kernel(const float* __restrict__ X, u16* __restrict__ Xb, int n4) {
  int i = blockIdx.x * 256 + threadIdx.x;
  if (i >= n4) return;
  f32x4 v = *reinterpret_cast<const f32x4*>(X + (size_t)i * 4);
  u32x2 p;
  p[0] = (unsigned)f2bf(v[0]) | ((unsigned)f2bf(v[1]) << 16);
  p[1] = (unsigned)f2bf(v[2]) | ((unsigned)f2bf(v[3]) << 16);
  *reinterpret_cast<u32x2*>(Xb + (size_t)i * 4) = p;
}

// ---- kernel 2: cast + transpose weights: Wt[qkv][n][k] --------------------
__global__ void cvt_w_kernel(const float* __restrict__ Wq, const float* __restrict__ Wk,
                             const float* __restrict__ Wv, u16* __restrict__ Wt) {
  int idx = blockIdx.x * 256 + threadIdx.x;
  int m = blockIdx.y;
  const float* W = (m == 0) ? Wq : (m == 1) ? Wk : Wv;
  int k = idx / DM, n = idx - k * DM;
  Wt[(size_t)m * DM * DM + (size_t)n * DM + k] = f2bf(W[idx]);
}

// ---- kernel 3: fused QKV GEMM (bf16 MFMA, 128x128 tile, BK=32) ------------
// v3: 3-stage pipeline. 3 LDS buffers, global prefetch 2 K-steps ahead
// (vmcnt(4) counted wait), register-fragment double-buffer: ds_read of step
// t+1 issued BEFORE the MFMAs of step t (LDS latency hides under MFMA), one
// barrier per K-step. Per-wave lgkm(0) drain precedes the barrier so buffer
// b's reads (iter b-1) complete >=1 barrier before its overwrite (iter b+1).
// XCD swizzle: 18 blocks sharing one A-slab (6 n-tiles x 3 qkv) -> same XCD;
// whole Wt (3.5 MB) stays L2-resident per XCD.
__global__ __launch_bounds__(256, 3)
void qkv_gemm_kernel(const u16* __restrict__ Xb, const u16* __restrict__ Wt,
                     const float* __restrict__ bq, const float* __restrict__ bk,
                     const float* __restrict__ bv,
                     u16* __restrict__ Qw, u16* __restrict__ Kw, u16* __restrict__ Vw) {
  __shared__ alignas(16) u16 As[3][128 * 32];
  __shared__ alignas(16) u16 Bs[3][128 * 32];

  const int tid = threadIdx.x;
  const int lane = tid & 63;
  const int wid = tid >> 6;
  const int wr = wid >> 1, wc = wid & 1;
  const int l15 = lane & 15, lq = lane >> 4;

  // XCD-aware work decode: grid (160,6,3) flat; xcd = flat%8. Per XCD:
  // 20 A-slabs (xi) x 18 (nt,qkv) consumers, consecutive j shares A-slab.
  const int flat = (blockIdx.z * 6 + blockIdx.y) * 160 + blockIdx.x;
  const int xcd = flat & 7;
  const int jj = flat >> 3;          // 0..359
  const int xi = jj / 18;            // 0..19  A-slab index on this XCD
  const int yz = jj - xi * 18;       // 0..17
  const int mt = xi * 8 + xcd;       // 0..159
  const int nt = yz % 6;
  const int qkv = yz / 6;

  const int b = mt / 5;
  const int t0 = (mt - b * 5) * 128;
  const int n0 = nt * 128;

  const u16* Wm = Wt + (size_t)qkv * DM * DM;
  const float* bias = (qkv == 0) ? bq : (qkv == 1) ? bk : bv;

  int tA0 = t0 + wid * 16 + l15;
  int tA1 = t0 + (wid + 4) * 16 + l15;
  int xr0 = b * SEQ + (tA0 < SEQ ? tA0 : SEQ - 1);
  int xr1 = b * SEQ + (tA1 < SEQ ? tA1 : SEQ - 1);
  const u16* gA0 = Xb + (size_t)xr0 * DM + lq * 8;
  const u16* gA1 = Xb + (size_t)xr1 * DM + lq * 8;
  const u16* gB0 = Wm + (size_t)(n0 + wid * 16 + l15) * DM + lq * 8;
  const u16* gB1 = Wm + (size_t)(n0 + (wid + 4) * 16 + l15) * DM + lq * 8;

  f32x4 acc[4][4];
#pragma unroll
  for (int i = 0; i < 4; ++i)
#pragma unroll
    for (int j = 0; j < 4; ++j)
#pragma unroll
      for (int r = 0; r < 4; ++r) acc[i][j][r] = 0.0f;

  auto stage = [&](int buf, int kt) {
    const int k0 = kt * 32;
    g2l16(gA0 + k0, &As[buf][wid * 512]);
    g2l16(gA1 + k0, &As[buf][(wid + 4) * 512]);
    g2l16(gB0 + k0, &Bs[buf][wid * 512]);
    g2l16(gB1 + k0, &Bs[buf][(wid + 4) * 512]);
  };

  const int NT = DM / 32;  // 24

  // prologue: 2 K-steps in flight
  stage(0, 0);
  stage(1, 1);
  asm volatile("s_waitcnt vmcnt(4)" ::: "memory");  // buf0 landed
  __builtin_amdgcn_s_barrier();

  bf16x8 af[2][4], bfq[2][4];
#pragma unroll
  for (int i = 0; i < 4; ++i)
    af[0][i] = *reinterpret_cast<const bf16x8*>(&As[0][((wr * 4 + i) * 64 + lane) * 8]);
#pragma unroll
  for (int j = 0; j < 4; ++j)
    bfq[0][j] = *reinterpret_cast<const bf16x8*>(&Bs[0][((wc * 4 + j) * 64 + lane) * 8]);

#pragma unroll
  for (int t = 0; t < NT; ++t) {
    if (t + 2 < NT) stage((t + 2) % 3, t + 2);
    if (t < NT - 1) {
      if (t + 2 < NT)
        asm volatile("s_waitcnt vmcnt(4)" ::: "memory");   // buf[t+1] landed
      else
        asm volatile("s_waitcnt vmcnt(0)" ::: "memory");   // tail drain
      asm volatile("s_waitcnt lgkmcnt(0)" ::: "memory");   // my reads of buf[t] done
      __builtin_amdgcn_s_barrier();  // all waves: buf[t+1] ready, buf[t+2] safe to overwrite
      const int nb = (t + 1) % 3;
      const int ns = (t + 1) & 1;
#pragma unroll
      for (int i = 0; i < 4; ++i)
        af[ns][i] = *reinterpret_cast<const bf16x8*>(&As[nb][((wr * 4 + i) * 64 + lane) * 8]);
#pragma unroll
      for (int j = 0; j < 4; ++j)
        bfq[ns][j] = *reinterpret_cast<const bf16x8*>(&Bs[nb][((wc * 4 + j) * 64 + lane) * 8]);
    }
    const int cs = t & 1;
#pragma unroll
    for (int i = 0; i < 4; ++i)
#pragma unroll
      for (int j = 0; j < 4; ++j)
        acc[i][j] = __builtin_amdgcn_mfma_f32_16x16x32_bf16(af[cs][i], bfq[cs][j], acc[i][j], 0, 0, 0);
  }

  const float sfold = 0.18033688011112042f;  // (1/sqrt(64)) * log2(e)
#pragma unroll
  for (int j = 0; j < 4; ++j) {
    int col = n0 + wc * 64 + j * 16 + l15;
    int h = col >> 6;
    int d = col & 63;
    float bb = bias[col];
#pragma unroll
    for (int i = 0; i < 4; ++i) {
      int trow = t0 + wr * 64 + i * 16 + lq * 4;
      if (qkv == 2) {
        float v0 = acc[i][j][0] + bb, v1 = acc[i][j][1] + bb;
        float v2 = acc[i][j][2] + bb, v3 = acc[i][j][3] + bb;
        u32x2 p;
        p[0] = (unsigned)f2bf(v0) | ((unsigned)f2bf(v1) << 16);
        p[1] = (unsigned)f2bf(v2) | ((unsigned)f2bf(v3) << 16);
        size_t o = ((size_t)(b * NH + h) * DH + d) * SP + trow;
        *reinterpret_cast<u32x2*>(Vw + o) = p;
      } else {
        u16* dst = ((qkv == 0) ? Qw : Kw) + ((size_t)(b * NH + h) * SP + trow) * DH + d;
#pragma unroll
        for (int r = 0; r < 4; ++r) {
          float v = acc[i][j][r] + bb;
          if (qkv == 0) v *= sfold;
          dst[r * DH] = f2bf(v);
        }
      }
    }
  }
}

// ---- kernel 4: flash attention v3 -----------------------------------------
// Block = 4 waves = 128 queries (wave owns 32 = 2 q-tiles of 16).
// Per 64-key chunk: K staged via global_load_lds (fragment-ordered 16B/lane),
// V staged via VGPR->ds_write (fragment-ordered 8B/lane), double-buffered,
// one barrier per chunk (m97 structure). S^T = K·Q^T keeps softmax in-lane;
// P stays in-lane as the K=16 PV B-frag (O^T = Vt·P^T). Zero shuffles.
// v3: XCD swizzle (5 q-blocks sharing one head's 160KB K/V -> same XCD L2)
// + s_setprio(1) around MFMA clusters (T5).
#if __has_builtin(__builtin_amdgcn_mfma_f32_16x16x16bf16_1k)
#define MFMA16(a, b, c) __builtin_amdgcn_mfma_f32_16x16x16bf16_1k(a, b, c, 0, 0, 0)
#define HAVE_MFMA16 1
#elif __has_builtin(__builtin_amdgcn_mfma_f32_16x16x16_bf16)
#define MFMA16(a, b, c) __builtin_amdgcn_mfma_f32_16x16x16_bf16(a, b, c, 0, 0, 0)
#define HAVE_MFMA16 1
#else
#define HAVE_MFMA16 0
#endif

__global__ __launch_bounds__(256)
void attn_kernel(const u16* __restrict__ Qw, const u16* __restrict__ Kw,
                 const u16* __restrict__ Vw, float* __restrict__ out) {
  // Kc: 8 entries (t,half) x 64 lanes x 16B = 8KB per buffer
  // Vc: 16 entries (dt,t)  x 64 lanes x  8B = 8KB per buffer
  __shared__ alignas(16) u16 Kc[2][8 * 64 * 8];
  __shared__ alignas(16) u16 Vc[2][16 * 64 * 4];

  const int tid = threadIdx.x;
  const int lane = tid & 63;
  const int wid = tid >> 6;
  const int l15 = lane & 15, lq = lane >> 4;

  // XCD-aware decode: grid (5, 384) -> flat 0..1919; each XCD gets a
  // contiguous range of 240 works = 48 complete (b,h) K/V groups.
  const int flat = blockIdx.y * 5 + blockIdx.x;
  const int w = (flat & 7) * 240 + (flat >> 3);
  const int qx = w % 5;
  const int bh = w / 5;
  const int b = bh / NH;
  const int h = bh - b * NH;
  const int q0 = qx * 128 + wid * 32;  // wave: queries q0..q0+31

  const u16* Qb = Qw + (size_t)bh * SP * DH;
  const u16* Kb = Kw + (size_t)bh * SP * DH;
  const u16* Vb = Vw + (size_t)bh * DH * SP;

  // Q B-frags: [qt][half], B[n=q=l15][k=half*32+lq*8+j]
  bf16x8 qf[2][2];
#pragma unroll
  for (int qt = 0; qt < 2; ++qt)
#pragma unroll
    for (int hf = 0; hf < 2; ++hf)
      qf[qt][hf] = *reinterpret_cast<const bf16x8*>(
          &Qb[(q0 + qt * 16 + l15) * DH + hf * 32 + lq * 8]);

  // staging source addresses (chunk-invariant parts)
  // K: wave stages entries e=2*wid+half: K[c0+wid*16+l15][half*32+lq*8..+8]
  const u16* gK = Kb + (size_t)(wid * 16 + l15) * DH + lq * 8;
  // V: wave stages entries e=4*wid+t: Vt[wid*16+l15][c0+t*16+lq*4..+4]
  const u16* gV = Vb + (size_t)(wid * 16 + l15) * SP + lq * 4;

  float mrow[2] = {-__builtin_inff(), -__builtin_inff()};
  float lrow[2] = {0.0f, 0.0f};
  f32x4 acc[2][4];  // [qt][dt]; d = dt*16+lq*4+r, q = q0+qt*16+l15
#pragma unroll
  for (int qt = 0; qt < 2; ++qt)
#pragma unroll
    for (int dt = 0; dt < 4; ++dt)
#pragma unroll
      for (int r = 0; r < 4; ++r) acc[qt][dt][r] = 0.0f;

  // ---- prologue: stage chunk 0 into buffer 0 ----
  g2l16(gK, &Kc[0][(wid * 2 + 0) * 512]);
  g2l16(gK + 32, &Kc[0][(wid * 2 + 1) * 512]);
  {
    u32x2 v[4];
#pragma unroll
    for (int t = 0; t < 4; ++t)
      v[t] = *reinterpret_cast<const u32x2*>(gV + t * 16);
#pragma unroll
    for (int t = 0; t < 4; ++t)
      *reinterpret_cast<u32x2*>(&Vc[0][((wid * 4 + t) * 64 + lane) * 4]) = v[t];
  }
  __syncthreads();

  for (int c = 0; c < NC; ++c) {
    const int cur = c & 1;
    const int c0 = c * 64;
    // ---- prefetch chunk c+1 (async; drained by end-of-loop barrier) ----
    u32x2 vn[4];
    if (c + 1 < NC) {
      const u16* gKn = gK + (size_t)(c0 + 64) * DH;
      g2l16(gKn, &Kc[cur ^ 1][(wid * 2 + 0) * 512]);
      g2l16(gKn + 32, &Kc[cur ^ 1][(wid * 2 + 1) * 512]);
#pragma unroll
      for (int t = 0; t < 4; ++t)
        vn[t] = *reinterpret_cast<const u32x2*>(gV + (c0 + 64) + t * 16);
    }

    // ---- S^T = K·Q^T from LDS K ----
    f32x4 s[2][4];
    __builtin_amdgcn_s_setprio(1);
#pragma unroll
    for (int t = 0; t < 4; ++t) {
      bf16x8 kf0 = *reinterpret_cast<const bf16x8*>(&Kc[cur][((t * 2 + 0) * 64 + lane) * 8]);
      bf16x8 kf1 = *reinterpret_cast<const bf16x8*>(&Kc[cur][((t * 2 + 1) * 64 + lane) * 8]);
#pragma unroll
      for (int qt = 0; qt < 2; ++qt) {
        f32x4 z;
#pragma unroll
        for (int r = 0; r < 4; ++r) z[r] = 0.0f;
        z = __builtin_amdgcn_mfma_f32_16x16x32_bf16(kf0, qf[qt][0], z, 0, 0, 0);
        z = __builtin_amdgcn_mfma_f32_16x16x32_bf16(kf1, qf[qt][1], z, 0, 0, 0);
        s[qt][t] = z;
      }
    }
    __builtin_amdgcn_s_setprio(0);
    // ---- mask padded keys (uniform branch, last chunk only) ----
    if (c0 + 64 > SEQ) {
#pragma unroll
      for (int qt = 0; qt < 2; ++qt)
#pragma unroll
        for (int t = 0; t < 4; ++t)
#pragma unroll
          for (int r = 0; r < 4; ++r) {
            int key = c0 + t * 16 + lq * 4 + r;
            s[qt][t][r] = (key < SEQ) ? s[qt][t][r] : -__builtin_inff();
          }
    }
    // ---- online softmax (in-lane over 16 + shfl 16,32) ----
    float alpha[2];
    unsigned int pku[2][4][2];
#pragma unroll
    for (int qt = 0; qt < 2; ++qt) {
      float mx = s[qt][0][0];
#pragma unroll
      for (int t = 0; t < 4; ++t)
#pragma unroll
        for (int r = 0; r < 4; ++r) mx = fmaxf(mx, s[qt][t][r]);
      mx = fmaxf(mx, __shfl_xor(mx, 16));
      mx = fmaxf(mx, __shfl_xor(mx, 32));
      float mn = fmaxf(mrow[qt], mx);
      alpha[qt] = __builtin_amdgcn_exp2f(mrow[qt] - mn);
      mrow[qt] = mn;
      float sm = 0.0f;
#pragma unroll
      for (int t = 0; t < 4; ++t) {
        float p0 = __builtin_amdgcn_exp2f(s[qt][t][0] - mn);
        float p1 = __builtin_amdgcn_exp2f(s[qt][t][1] - mn);
        float p2 = __builtin_amdgcn_exp2f(s[qt][t][2] - mn);
        float p3 = __builtin_amdgcn_exp2f(s[qt][t][3] - mn);
        sm += (p0 + p1) + (p2 + p3);
        pku[qt][t][0] = pack_bf2(p0, p1);
        pku[qt][t][1] = pack_bf2(p2, p3);
      }
      sm += __shfl_xor(sm, 16);
      sm += __shfl_xor(sm, 32);
      lrow[qt] = lrow[qt] * alpha[qt] + sm;
    }

#if HAVE_MFMA16
    // ---- PV: O^T = Vt·P^T (K=16 MFMA; vf shared across q-tiles) ----
    __builtin_amdgcn_s_setprio(1);
#pragma unroll
    for (int dt = 0; dt < 4; ++dt) {
      bf16x4 vf[4];
#pragma unroll
      for (int t = 0; t < 4; ++t)
        vf[t] = *reinterpret_cast<const bf16x4*>(&Vc[cur][((dt * 4 + t) * 64 + lane) * 4]);
#pragma unroll
      for (int qt = 0; qt < 2; ++qt) {
        f32x4 a = acc[qt][dt];
#pragma unroll
        for (int r = 0; r < 4; ++r) a[r] *= alpha[qt];
#pragma unroll
        for (int t = 0; t < 4; ++t) {
          bf16x4 pf = __builtin_bit_cast(bf16x4, u32x2{pku[qt][t][0], pku[qt][t][1]});
          a = MFMA16(vf[t], pf, a);
        }
        acc[qt][dt] = a;
      }
    }
    __builtin_amdgcn_s_setprio(0);
#else
    // ---- fallback: K=32 MFMA, B-frag via bpermute (v2-verified pattern) ----
#pragma unroll
    for (int qt = 0; qt < 2; ++qt) {
      unsigned int bfrag[2][4];
#pragma unroll
      for (int hh = 0; hh < 2; ++hh)
#pragma unroll
        for (int w2 = 0; w2 < 4; ++w2) {
          int srcl = l15 + 16 * (2 * (lq & 1) + (w2 >> 1));
          unsigned int lo = (unsigned int)__shfl((int)pku[qt][2 * hh][w2 & 1], srcl);
          unsigned int hi = (unsigned int)__shfl((int)pku[qt][2 * hh + 1][w2 & 1], srcl);
          bfrag[hh][w2] = (lq < 2) ? lo : hi;
        }
#pragma unroll
      for (int dt = 0; dt < 4; ++dt) {
        f32x4 a = acc[qt][dt];
#pragma unroll
        for (int r = 0; r < 4; ++r) a[r] *= alpha[qt];
#pragma unroll
        for (int hh = 0; hh < 2; ++hh) {
          u32x2 w0 = *reinterpret_cast<const u32x2*>(&Vc[cur][((dt * 4 + 2 * hh) * 64 + lane) * 4]);
          u32x2 w1 = *reinterpret_cast<const u32x2*>(&Vc[cur][((dt * 4 + 2 * hh + 1) * 64 + lane) * 4]);
          u32x4 vw = {w0[0], w0[1], w1[0], w1[1]};
          u32x4 pw = {bfrag[hh][0], bfrag[hh][1], bfrag[hh][2], bfrag[hh][3]};
          a = __builtin_amdgcn_mfma_f32_16x16x32_bf16(
              __builtin_bit_cast(bf16x8, vw), __builtin_bit_cast(bf16x8, pw), a, 0, 0, 0);
        }
        acc[qt][dt] = a;
      }
    }
#endif

    // ---- write prefetched V into the other buffer, then barrier ----
    if (c + 1 < NC) {
#pragma unroll
      for (int t = 0; t < 4; ++t)
        *reinterpret_cast<u32x2*>(&Vc[cur ^ 1][((wid * 4 + t) * 64 + lane) * 4]) = vn[t];
    }
    __syncthreads();
  }

  // ---- epilogue: direct stores (lane holds 4 consecutive d -> 16B store) ----
#pragma unroll
  for (int qt = 0; qt < 2; ++qt) {
    int q = q0 + qt * 16 + l15;
    if (q < SEQ) {
      float rl = 1.0f / lrow[qt];
      float* orow = out + ((size_t)b * SEQ + q) * DM + h * DH;
#pragma unroll
      for (int dt = 0; dt < 4; ++dt) {
        f32x4 v = acc[qt][dt];
#pragma unroll
        for (int r = 0; r < 4; ++r) v[r] *= rl;
        *reinterpret_cast<f32x4*>(&orow[dt * 16 + lq * 4]) = v;
      }
    }
  }
}

extern "C" void kernel_launch(void* const* d_in, const int* in_sizes, int n_in,
                              void* d_out, int out_size, void* d_ws, size_t ws_size,
                              hipStream_t stream) {
  (void)in_sizes; (void)n_in; (void)out_size; (void)ws_size;
  const float* X  = (const float*)d_in[0];
  const float* Wq = (const float*)d_in[1];
  const float* bq = (const float*)d_in[2];
  const float* Wk = (const float*)d_in[3];
  const float* bk = (const float*)d_in[4];
  const float* Wv = (const float*)d_in[5];
  const float* bv = (const float*)d_in[6];
  float* out = (float*)d_out;

  char* ws = (char*)d_ws;
  u16* Xb = (u16*)ws;
  u16* Wt = (u16*)(ws + 28366848);
  u16* Qw = (u16*)(ws + 28366848 + 3538944);
  u16* Kw = Qw + (size_t)NB * NH * SP * DH;
  u16* Vw = Kw + (size_t)NB * NH * SP * DH;

  cvt_x_kernel<<<dim3(13848), 256, 0, stream>>>(X, Xb, 3545088);
  cvt_w_kernel<<<dim3(2304, 3), 256, 0, stream>>>(Wq, Wk, Wv, Wt);
  qkv_gemm_kernel<<<dim3(160, 6, 3), 256, 0, stream>>>(Xb, Wt, bq, bk, bv, Qw, Kw, Vw);
  attn_kernel<<<dim3(5, NB * NH), 256, 0, stream>>>(Qw, Kw, Vw, out);
}

// Round 3
// 343.598 us; speedup vs baseline: 1.1026x; 1.0593x over previous
//
#include <hip/hip_runtime.h>

// B=32, S=577, D=768, H=12, Dh=64. fp32 in/out, bf16 MFMA compute.
#define NB 32
#define SEQ 577
#define SP 640      // padded seq (5*128, 10*64)
#define DM 768
#define NH 12
#define DH 64
#define NC 10       // key chunks of 64

typedef __attribute__((ext_vector_type(8))) short bf16x8;   // K=32 MFMA A/B frag
typedef __attribute__((ext_vector_type(4))) short bf16x4;   // K=16 MFMA A/B frag
typedef __attribute__((ext_vector_type(4))) float f32x4;
typedef __attribute__((ext_vector_type(2))) unsigned int u32x2;
typedef __attribute__((ext_vector_type(4))) unsigned int u32x4;
typedef unsigned short u16;

__device__ __forceinline__ u16 f2bf(float f) {  // RNE float->bf16
  unsigned int u = __builtin_bit_cast(unsigned int, f);
  u += 0x7fffu + ((u >> 16) & 1u);
  return (u16)(u >> 16);
}

// pack two fp32 -> bf16 pair (round-half-up) in one v_perm
__device__ __forceinline__ unsigned int pack_bf2(float a, float b) {
  unsigned int ua = __builtin_bit_cast(unsigned int, a) + 0x8000u;
  unsigned int ub = __builtin_bit_cast(unsigned int, b) + 0x8000u;
  return __builtin_amdgcn_perm(ub, ua, 0x07060302u);  // lo16=bf(a), hi16=bf(b)
}

__device__ __forceinline__ void g2l16(const void* g, void* lds) {
  __builtin_amdgcn_global_load_lds(
      (const __attribute__((address_space(1))) void*)g,
      (__attribute__((address_space(3))) void*)lds, 16, 0, 0);
}

// ---- kernel 1: fp32 -> bf16 cast of hidden_states -------------------------
__global__ void cvt_x_kernel(const float* __restrict__ X, u16* __restrict__ Xb, int n4) {
  int i = blockIdx.x * 256 + threadIdx.x;
  if (i >= n4) return;
  f32x4 v = *reinterpret_cast<const f32x4*>(X + (size_t)i * 4);
  u32x2 p;
  p[0] = (unsigned)f2bf(v[0]) | ((unsigned)f2bf(v[1]) << 16);
  p[1] = (unsigned)f2bf(v[2]) | ((unsigned)f2bf(v[3]) << 16);
  *reinterpret_cast<u32x2*>(Xb + (size_t)i * 4) = p;
}

// ---- kernel 2: cast + transpose weights: Wt[qkv][n][k] --------------------
__global__ void cvt_w_kernel(const float* __restrict__ Wq, const float* __restrict__ Wk,
                             const float* __restrict__ Wv, u16* __restrict__ Wt) {
  int idx = blockIdx.x * 256 + threadIdx.x;
  int m = blockIdx.y;
  const float* W = (m == 0) ? Wq : (m == 1) ? Wk : Wv;
  int k = idx / DM, n = idx - k * DM;
  Wt[(size_t)m * DM * DM + (size_t)n * DM + k] = f2bf(W[idx]);
}

// ---- kernel 3: fused QKV GEMM (bf16 MFMA, 256x256 tile, BK=64) ------------
// v4: 8-phase-template port (T3+T4+T5). 512 threads = 8 waves (2M x 4N),
// wave output 128x64 (acc 8x4), LDS 128KB double-buffered, fragment-ordered
// staging (LDS linear dest, pre-permuted global src -> conflict-free b128
// reads, no swizzle needed). Per K-tile (BK=64): 4 phases, each
// {ds_read subtile || stage issue -> barrier -> setprio+16 MFMA -> barrier};
// stages front-loaded in p0/p1 so the single per-K-tile vmcnt(0) boundary
// has >=2 phases of load-latency slack (counted-wait effect, T4).
// M-tiles of 256 span batch boundaries: per-lane r/640 decode on staging
// and epilogue (640%4==0 keeps 4-row vector writes within one batch).
__global__ __launch_bounds__(512, 2)
void qkv_gemm_kernel(const u16* __restrict__ Xb, const u16* __restrict__ Wt,
                     const float* __restrict__ bq, const float* __restrict__ bk,
                     const float* __restrict__ bv,
                     u16* __restrict__ Qw, u16* __restrict__ Kw, u16* __restrict__ Vw) {
  // entry e = row_tile*2 + k_half; slot = (e*64 + lane)*8 u16 (1KB/entry)
  __shared__ alignas(16) u16 As[2][32 * 512];
  __shared__ alignas(16) u16 Bs[2][32 * 512];

  const int tid = threadIdx.x;
  const int lane = tid & 63;
  const int wid = tid >> 6;          // 0..7
  const int wm = wid >> 2, wn = wid & 3;
  const int l15 = lane & 15, lq = lane >> 4;

  // XCD swizzle: 720 blocks = 8 XCDs x 90; 9 consumers (3 nt x 3 qkv) of
  // each 384KB A-slab adjacent on one XCD (Wt 3.5MB ~ L2-resident).
  const int flat = (blockIdx.z * 3 + blockIdx.y) * 80 + blockIdx.x;
  const int xcd = flat & 7;
  const int j8 = flat >> 3;          // 0..89
  const int xi = j8 / 9;             // 0..9
  const int yz = j8 - xi * 9;        // 0..8
  const int mt = xi * 8 + xcd;       // 0..79
  const int nt = yz % 3;
  const int qkv = yz / 3;

  const u16* Wm = Wt + (size_t)qkv * DM * DM;
  const float* bias = (qkv == 0) ? bq : (qkv == 1) ? bk : bv;

  // staging source pointers: wave stages A entries wid*4..+3 and B same
  const u16* gA[4];
  const u16* gB[4];
#pragma unroll
  for (int s = 0; s < 4; ++s) {
    const int e = wid * 4 + s;       // 0..31
    const int ti = e >> 1, hh = e & 1;
    int r = mt * 256 + ti * 16 + l15;
    int br = r / SP;
    int tr = r - br * SP;
    if (tr >= SEQ) tr = SEQ - 1;     // clamp padded rows (finite garbage)
    gA[s] = Xb + (size_t)(br * SEQ + tr) * DM + hh * 32 + lq * 8;
    gB[s] = Wm + (size_t)(nt * 256 + ti * 16 + l15) * DM + hh * 32 + lq * 8;
  }

  f32x4 acc[8][4];
#pragma unroll
  for (int i = 0; i < 8; ++i)
#pragma unroll
    for (int j = 0; j < 4; ++j)
#pragma unroll
      for (int r = 0; r < 4; ++r) acc[i][j][r] = 0.0f;

  auto stageA = [&](int buf, int kt) {
#pragma unroll
    for (int s = 0; s < 4; ++s)
      g2l16(gA[s] + kt * 64, &As[buf][(wid * 4 + s) * 512]);
  };
  auto stageB = [&](int buf, int kt) {
#pragma unroll
    for (int s = 0; s < 4; ++s)
      g2l16(gB[s] + kt * 64, &Bs[buf][(wid * 4 + s) * 512]);
  };

  // prologue: K-tile 0 into buf 0
  stageA(0, 0);
  stageB(0, 0);
  asm volatile("s_waitcnt vmcnt(0)" ::: "memory");
  __builtin_amdgcn_s_barrier();

  const int NKT = DM / 64;  // 12
  for (int kt = 0; kt < NKT; ++kt) {
    const int buf = kt & 1;
    const bool more = (kt + 1 < NKT);
    bf16x8 af[4][2], bfr[4][2];

    // ---- p0: read A(i=0..3) + B(j=0..1); stage next A ----
#pragma unroll
    for (int i = 0; i < 4; ++i)
#pragma unroll
      for (int h = 0; h < 2; ++h)
        af[i][h] = *reinterpret_cast<const bf16x8*>(
            &As[buf][(((wm * 8 + i) * 2 + h) * 64 + lane) * 8]);
#pragma unroll
    for (int j = 0; j < 2; ++j)
#pragma unroll
      for (int h = 0; h < 2; ++h)
        bfr[j][h] = *reinterpret_cast<const bf16x8*>(
            &Bs[buf][(((wn * 4 + j) * 2 + h) * 64 + lane) * 8]);
    if (more) stageA(buf ^ 1, kt + 1);
    __builtin_amdgcn_s_barrier();
    __builtin_amdgcn_s_setprio(1);
#pragma unroll
    for (int i = 0; i < 4; ++i)
#pragma unroll
      for (int j = 0; j < 2; ++j)
#pragma unroll
        for (int h = 0; h < 2; ++h)
          acc[i][j] = __builtin_amdgcn_mfma_f32_16x16x32_bf16(af[i][h], bfr[j][h], acc[i][j], 0, 0, 0);
    __builtin_amdgcn_s_setprio(0);
    __builtin_amdgcn_s_barrier();

    // ---- p1: read B(j=2..3); stage next B ----
#pragma unroll
    for (int j = 2; j < 4; ++j)
#pragma unroll
      for (int h = 0; h < 2; ++h)
        bfr[j][h] = *reinterpret_cast<const bf16x8*>(
            &Bs[buf][(((wn * 4 + j) * 2 + h) * 64 + lane) * 8]);
    if (more) stageB(buf ^ 1, kt + 1);
    __builtin_amdgcn_s_barrier();
    __builtin_amdgcn_s_setprio(1);
#pragma unroll
    for (int i = 0; i < 4; ++i)
#pragma unroll
      for (int j = 2; j < 4; ++j)
#pragma unroll
        for (int h = 0; h < 2; ++h)
          acc[i][j] = __builtin_amdgcn_mfma_f32_16x16x32_bf16(af[i][h], bfr[j][h], acc[i][j], 0, 0, 0);
    __builtin_amdgcn_s_setprio(0);
    __builtin_amdgcn_s_barrier();

    // ---- p2: read A(i=4..7); MFMA (i4-7 x j2-3) ----
#pragma unroll
    for (int i = 0; i < 4; ++i)
#pragma unroll
      for (int h = 0; h < 2; ++h)
        af[i][h] = *reinterpret_cast<const bf16x8*>(
            &As[buf][(((wm * 8 + 4 + i) * 2 + h) * 64 + lane) * 8]);
    __builtin_amdgcn_s_barrier();
    __builtin_amdgcn_s_setprio(1);
#pragma unroll
    for (int i = 0; i < 4; ++i)
#pragma unroll
      for (int j = 2; j < 4; ++j)
#pragma unroll
        for (int h = 0; h < 2; ++h)
          acc[4 + i][j] = __builtin_amdgcn_mfma_f32_16x16x32_bf16(af[i][h], bfr[j][h], acc[4 + i][j], 0, 0, 0);
    __builtin_amdgcn_s_setprio(0);
    __builtin_amdgcn_s_barrier();

    // ---- p3: MFMA (i4-7 x j0-1); K-tile boundary ----
    __builtin_amdgcn_s_setprio(1);
#pragma unroll
    for (int i = 0; i < 4; ++i)
#pragma unroll
      for (int j = 0; j < 2; ++j)
#pragma unroll
        for (int h = 0; h < 2; ++h)
          acc[4 + i][j] = __builtin_amdgcn_mfma_f32_16x16x32_bf16(af[i][h], bfr[j][h], acc[4 + i][j], 0, 0, 0);
    __builtin_amdgcn_s_setprio(0);
    asm volatile("s_waitcnt vmcnt(0)" ::: "memory");  // next-tile stages landed
    __builtin_amdgcn_s_barrier();
  }

  const float sfold = 0.18033688011112042f;  // (1/sqrt(64)) * log2(e)
#pragma unroll
  for (int j = 0; j < 4; ++j) {
    const int col = nt * 256 + wn * 64 + j * 16 + l15;
    const int h = col >> 6;
    const int d = col & 63;
    const float bb = bias[col];
#pragma unroll
    for (int i = 0; i < 8; ++i) {
      const int rg = mt * 256 + wm * 128 + i * 16 + lq * 4;
      const int br = rg / SP;
      const int tr = rg - br * SP;   // 640%4==0 -> tr..tr+3 same batch
      if (qkv == 2) {
        float v0 = acc[i][j][0] + bb, v1 = acc[i][j][1] + bb;
        float v2 = acc[i][j][2] + bb, v3 = acc[i][j][3] + bb;
        u32x2 p;
        p[0] = (unsigned)f2bf(v0) | ((unsigned)f2bf(v1) << 16);
        p[1] = (unsigned)f2bf(v2) | ((unsigned)f2bf(v3) << 16);
        size_t o = ((size_t)(br * NH + h) * DH + d) * SP + tr;
        *reinterpret_cast<u32x2*>(Vw + o) = p;
      } else {
        u16* dst = ((qkv == 0) ? Qw : Kw) + ((size_t)(br * NH + h) * SP + tr) * DH + d;
#pragma unroll
        for (int r = 0; r < 4; ++r) {
          float v = acc[i][j][r] + bb;
          if (qkv == 0) v *= sfold;
          dst[r * DH] = f2bf(v);
        }
      }
    }
  }
}

// ---- kernel 4: flash attention v3 -----------------------------------------
// Block = 4 waves = 128 queries (wave owns 32 = 2 q-tiles of 16).
// Per 64-key chunk: K staged via global_load_lds (fragment-ordered 16B/lane),
// V staged via VGPR->ds_write (fragment-ordered 8B/lane), double-buffered,
// one barrier per chunk (m97 structure). S^T = K·Q^T keeps softmax in-lane;
// P stays in-lane as the K=16 PV B-frag (O^T = Vt·P^T). Zero shuffles.
// XCD swizzle (5 q-blocks sharing one head's 160KB K/V -> same XCD L2)
// + s_setprio(1) around MFMA clusters (T5).
#if __has_builtin(__builtin_amdgcn_mfma_f32_16x16x16bf16_1k)
#define MFMA16(a, b, c) __builtin_amdgcn_mfma_f32_16x16x16bf16_1k(a, b, c, 0, 0, 0)
#define HAVE_MFMA16 1
#elif __has_builtin(__builtin_amdgcn_mfma_f32_16x16x16_bf16)
#define MFMA16(a, b, c) __builtin_amdgcn_mfma_f32_16x16x16_bf16(a, b, c, 0, 0, 0)
#define HAVE_MFMA16 1
#else
#define HAVE_MFMA16 0
#endif

__global__ __launch_bounds__(256)
void attn_kernel(const u16* __restrict__ Qw, const u16* __restrict__ Kw,
                 const u16* __restrict__ Vw, float* __restrict__ out) {
  // Kc: 8 entries (t,half) x 64 lanes x 16B = 8KB per buffer
  // Vc: 16 entries (dt,t)  x 64 lanes x  8B = 8KB per buffer
  __shared__ alignas(16) u16 Kc[2][8 * 64 * 8];
  __shared__ alignas(16) u16 Vc[2][16 * 64 * 4];

  const int tid = threadIdx.x;
  const int lane = tid & 63;
  const int wid = tid >> 6;
  const int l15 = lane & 15, lq = lane >> 4;

  // XCD-aware decode: grid (5, 384) -> flat 0..1919; each XCD gets a
  // contiguous range of 240 works = 48 complete (b,h) K/V groups.
  const int flat = blockIdx.y * 5 + blockIdx.x;
  const int w = (flat & 7) * 240 + (flat >> 3);
  const int qx = w % 5;
  const int bh = w / 5;
  const int b = bh / NH;
  const int h = bh - b * NH;
  const int q0 = qx * 128 + wid * 32;  // wave: queries q0..q0+31

  const u16* Qb = Qw + (size_t)bh * SP * DH;
  const u16* Kb = Kw + (size_t)bh * SP * DH;
  const u16* Vb = Vw + (size_t)bh * DH * SP;

  // Q B-frags: [qt][half], B[n=q=l15][k=half*32+lq*8+j]
  bf16x8 qf[2][2];
#pragma unroll
  for (int qt = 0; qt < 2; ++qt)
#pragma unroll
    for (int hf = 0; hf < 2; ++hf)
      qf[qt][hf] = *reinterpret_cast<const bf16x8*>(
          &Qb[(q0 + qt * 16 + l15) * DH + hf * 32 + lq * 8]);

  // staging source addresses (chunk-invariant parts)
  // K: wave stages entries e=2*wid+half: K[c0+wid*16+l15][half*32+lq*8..+8]
  const u16* gK = Kb + (size_t)(wid * 16 + l15) * DH + lq * 8;
  // V: wave stages entries e=4*wid+t: Vt[wid*16+l15][c0+t*16+lq*4..+4]
  const u16* gV = Vb + (size_t)(wid * 16 + l15) * SP + lq * 4;

  float mrow[2] = {-__builtin_inff(), -__builtin_inff()};
  float lrow[2] = {0.0f, 0.0f};
  f32x4 acc[2][4];  // [qt][dt]; d = dt*16+lq*4+r, q = q0+qt*16+l15
#pragma unroll
  for (int qt = 0; qt < 2; ++qt)
#pragma unroll
    for (int dt = 0; dt < 4; ++dt)
#pragma unroll
      for (int r = 0; r < 4; ++r) acc[qt][dt][r] = 0.0f;

  // ---- prologue: stage chunk 0 into buffer 0 ----
  g2l16(gK, &Kc[0][(wid * 2 + 0) * 512]);
  g2l16(gK + 32, &Kc[0][(wid * 2 + 1) * 512]);
  {
    u32x2 v[4];
#pragma unroll
    for (int t = 0; t < 4; ++t)
      v[t] = *reinterpret_cast<const u32x2*>(gV + t * 16);
#pragma unroll
    for (int t = 0; t < 4; ++t)
      *reinterpret_cast<u32x2*>(&Vc[0][((wid * 4 + t) * 64 + lane) * 4]) = v[t];
  }
  __syncthreads();

  for (int c = 0; c < NC; ++c) {
    const int cur = c & 1;
    const int c0 = c * 64;
    // ---- prefetch chunk c+1 (async; drained by end-of-loop barrier) ----
    u32x2 vn[4];
    if (c + 1 < NC) {
      const u16* gKn = gK + (size_t)(c0 + 64) * DH;
      g2l16(gKn, &Kc[cur ^ 1][(wid * 2 + 0) * 512]);
      g2l16(gKn + 32, &Kc[cur ^ 1][(wid * 2 + 1) * 512]);
#pragma unroll
      for (int t = 0; t < 4; ++t)
        vn[t] = *reinterpret_cast<const u32x2*>(gV + (c0 + 64) + t * 16);
    }

    // ---- S^T = K·Q^T from LDS K ----
    f32x4 s[2][4];
    __builtin_amdgcn_s_setprio(1);
#pragma unroll
    for (int t = 0; t < 4; ++t) {
      bf16x8 kf0 = *reinterpret_cast<const bf16x8*>(&Kc[cur][((t * 2 + 0) * 64 + lane) * 8]);
      bf16x8 kf1 = *reinterpret_cast<const bf16x8*>(&Kc[cur][((t * 2 + 1) * 64 + lane) * 8]);
#pragma unroll
      for (int qt = 0; qt < 2; ++qt) {
        f32x4 z;
#pragma unroll
        for (int r = 0; r < 4; ++r) z[r] = 0.0f;
        z = __builtin_amdgcn_mfma_f32_16x16x32_bf16(kf0, qf[qt][0], z, 0, 0, 0);
        z = __builtin_amdgcn_mfma_f32_16x16x32_bf16(kf1, qf[qt][1], z, 0, 0, 0);
        s[qt][t] = z;
      }
    }
    __builtin_amdgcn_s_setprio(0);
    // ---- mask padded keys (uniform branch, last chunk only) ----
    if (c0 + 64 > SEQ) {
#pragma unroll
      for (int qt = 0; qt < 2; ++qt)
#pragma unroll
        for (int t = 0; t < 4; ++t)
#pragma unroll
          for (int r = 0; r < 4; ++r) {
            int key = c0 + t * 16 + lq * 4 + r;
            s[qt][t][r] = (key < SEQ) ? s[qt][t][r] : -__builtin_inff();
          }
    }
    // ---- online softmax (in-lane over 16 + shfl 16,32) ----
    float alpha[2];
    unsigned int pku[2][4][2];
#pragma unroll
    for (int qt = 0; qt < 2; ++qt) {
      float mx = s[qt][0][0];
#pragma unroll
      for (int t = 0; t < 4; ++t)
#pragma unroll
        for (int r = 0; r < 4; ++r) mx = fmaxf(mx, s[qt][t][r]);
      mx = fmaxf(mx, __shfl_xor(mx, 16));
      mx = fmaxf(mx, __shfl_xor(mx, 32));
      float mn = fmaxf(mrow[qt], mx);
      alpha[qt] = __builtin_amdgcn_exp2f(mrow[qt] - mn);
      mrow[qt] = mn;
      float sm = 0.0f;
#pragma unroll
      for (int t = 0; t < 4; ++t) {
        float p0 = __builtin_amdgcn_exp2f(s[qt][t][0] - mn);
        float p1 = __builtin_amdgcn_exp2f(s[qt][t][1] - mn);
        float p2 = __builtin_amdgcn_exp2f(s[qt][t][2] - mn);
        float p3 = __builtin_amdgcn_exp2f(s[qt][t][3] - mn);
        sm += (p0 + p1) + (p2 + p3);
        pku[qt][t][0] = pack_bf2(p0, p1);
        pku[qt][t][1] = pack_bf2(p2, p3);
      }
      sm += __shfl_xor(sm, 16);
      sm += __shfl_xor(sm, 32);
      lrow[qt] = lrow[qt] * alpha[qt] + sm;
    }

#if HAVE_MFMA16
    // ---- PV: O^T = Vt·P^T (K=16 MFMA; vf shared across q-tiles) ----
    __builtin_amdgcn_s_setprio(1);
#pragma unroll
    for (int dt = 0; dt < 4; ++dt) {
      bf16x4 vf[4];
#pragma unroll
      for (int t = 0; t < 4; ++t)
        vf[t] = *reinterpret_cast<const bf16x4*>(&Vc[cur][((dt * 4 + t) * 64 + lane) * 4]);
#pragma unroll
      for (int qt = 0; qt < 2; ++qt) {
        f32x4 a = acc[qt][dt];
#pragma unroll
        for (int r = 0; r < 4; ++r) a[r] *= alpha[qt];
#pragma unroll
        for (int t = 0; t < 4; ++t) {
          bf16x4 pf = __builtin_bit_cast(bf16x4, u32x2{pku[qt][t][0], pku[qt][t][1]});
          a = MFMA16(vf[t], pf, a);
        }
        acc[qt][dt] = a;
      }
    }
    __builtin_amdgcn_s_setprio(0);
#else
    // ---- fallback: K=32 MFMA, B-frag via bpermute (v2-verified pattern) ----
#pragma unroll
    for (int qt = 0; qt < 2; ++qt) {
      unsigned int bfrag[2][4];
#pragma unroll
      for (int hh = 0; hh < 2; ++hh)
#pragma unroll
        for (int w2 = 0; w2 < 4; ++w2) {
          int srcl = l15 + 16 * (2 * (lq & 1) + (w2 >> 1));
          unsigned int lo = (unsigned int)__shfl((int)pku[qt][2 * hh][w2 & 1], srcl);
          unsigned int hi = (unsigned int)__shfl((int)pku[qt][2 * hh + 1][w2 & 1], srcl);
          bfrag[hh][w2] = (lq < 2) ? lo : hi;
        }
#pragma unroll
      for (int dt = 0; dt < 4; ++dt) {
        f32x4 a = acc[qt][dt];
#pragma unroll
        for (int r = 0; r < 4; ++r) a[r] *= alpha[qt];
#pragma unroll
        for (int hh = 0; hh < 2; ++hh) {
          u32x2 w0 = *reinterpret_cast<const u32x2*>(&Vc[cur][((dt * 4 + 2 * hh) * 64 + lane) * 4]);
          u32x2 w1 = *reinterpret_cast<const u32x2*>(&Vc[cur][((dt * 4 + 2 * hh + 1) * 64 + lane) * 4]);
          u32x4 vw = {w0[0], w0[1], w1[0], w1[1]};
          u32x4 pw = {bfrag[hh][0], bfrag[hh][1], bfrag[hh][2], bfrag[hh][3]};
          a = __builtin_amdgcn_mfma_f32_16x16x32_bf16(
              __builtin_bit_cast(bf16x8, vw), __builtin_bit_cast(bf16x8, pw), a, 0, 0, 0);
        }
        acc[qt][dt] = a;
      }
    }
#endif

    // ---- write prefetched V into the other buffer, then barrier ----
    if (c + 1 < NC) {
#pragma unroll
      for (int t = 0; t < 4; ++t)
        *reinterpret_cast<u32x2*>(&Vc[cur ^ 1][((wid * 4 + t) * 64 + lane) * 4]) = vn[t];
    }
    __syncthreads();
  }

  // ---- epilogue: direct stores (lane holds 4 consecutive d -> 16B store) ----
#pragma unroll
  for (int qt = 0; qt < 2; ++qt) {
    int q = q0 + qt * 16 + l15;
    if (q < SEQ) {
      float rl = 1.0f / lrow[qt];
      float* orow = out + ((size_t)b * SEQ + q) * DM + h * DH;
#pragma unroll
      for (int dt = 0; dt < 4; ++dt) {
        f32x4 v = acc[qt][dt];
#pragma unroll
        for (int r = 0; r < 4; ++r) v[r] *= rl;
        *reinterpret_cast<f32x4*>(&orow[dt * 16 + lq * 4]) = v;
      }
    }
  }
}

extern "C" void kernel_launch(void* const* d_in, const int* in_sizes, int n_in,
                              void* d_out, int out_size, void* d_ws, size_t ws_size,
                              hipStream_t stream) {
  (void)in_sizes; (void)n_in; (void)out_size; (void)ws_size;
  const float* X  = (const float*)d_in[0];
  const float* Wq = (const float*)d_in[1];
  const float* bq = (const float*)d_in[2];
  const float* Wk = (const float*)d_in[3];
  const float* bk = (const float*)d_in[4];
  const float* Wv = (const float*)d_in[5];
  const float* bv = (const float*)d_in[6];
  float* out = (float*)d_out;

  char* ws = (char*)d_ws;
  u16* Xb = (u16*)ws;
  u16* Wt = (u16*)(ws + 28366848);
  u16* Qw = (u16*)(ws + 28366848 + 3538944);
  u16* Kw = Qw + (size_t)NB * NH * SP * DH;
  u16* Vw = Kw + (size_t)NB * NH * SP * DH;

  cvt_x_kernel<<<dim3(13848), 256, 0, stream>>>(X, Xb, 3545088);
  cvt_w_kernel<<<dim3(2304, 3), 256, 0, stream>>>(Wq, Wk, Wv, Wt);
  qkv_gemm_kernel<<<dim3(80, 3, 3), 512, 0, stream>>>(Xb, Wt, bq, bk, bv, Qw, Kw, Vw);
  attn_kernel<<<dim3(5, NB * NH), 256, 0, stream>>>(Qw, Kw, Vw, out);
}

// Round 4
// 326.644 us; speedup vs baseline: 1.1599x; 1.0519x over previous
//
#include <hip/hip_runtime.h>

// B=32, S=577, D=768, H=12, Dh=64. fp32 in/out, bf16 MFMA compute.
#define NB 32
#define SEQ 577
#define SP 640      // padded seq (5*128, 10*64)
#define DM 768
#define NH 12
#define DH 64
#define NC 10       // key chunks of 64

typedef __attribute__((ext_vector_type(8))) short bf16x8;   // K=32 MFMA A/B frag
typedef __attribute__((ext_vector_type(4))) short bf16x4;   // K=16 MFMA A/B frag
typedef __attribute__((ext_vector_type(4))) float f32x4;
typedef __attribute__((ext_vector_type(2))) unsigned int u32x2;
typedef __attribute__((ext_vector_type(4))) unsigned int u32x4;
typedef unsigned short u16;

__device__ __forceinline__ u16 f2bf(float f) {  // RNE float->bf16
  unsigned int u = __builtin_bit_cast(unsigned int, f);
  u += 0x7fffu + ((u >> 16) & 1u);
  return (u16)(u >> 16);
}

// pack two fp32 -> bf16 pair (round-half-up) in one v_perm
__device__ __forceinline__ unsigned int pack_bf2(float a, float b) {
  unsigned int ua = __builtin_bit_cast(unsigned int, a) + 0x8000u;
  unsigned int ub = __builtin_bit_cast(unsigned int, b) + 0x8000u;
  return __builtin_amdgcn_perm(ub, ua, 0x07060302u);  // lo16=bf(a), hi16=bf(b)
}

__device__ __forceinline__ void g2l16(const void* g, void* lds) {
  __builtin_amdgcn_global_load_lds(
      (const __attribute__((address_space(1))) void*)g,
      (__attribute__((address_space(3))) void*)lds, 16, 0, 0);
}

// ---- kernel 1: fp32 -> bf16 cast of hidden_states -------------------------
__global__ void cvt_x_kernel(const float* __restrict__ X, u16* __restrict__ Xb, int n4) {
  int i = blockIdx.x * 256 + threadIdx.x;
  if (i >= n4) return;
  f32x4 v = *reinterpret_cast<const f32x4*>(X + (size_t)i * 4);
  u32x2 p;
  p[0] = (unsigned)f2bf(v[0]) | ((unsigned)f2bf(v[1]) << 16);
  p[1] = (unsigned)f2bf(v[2]) | ((unsigned)f2bf(v[3]) << 16);
  *reinterpret_cast<u32x2*>(Xb + (size_t)i * 4) = p;
}

// ---- kernel 2: cast + transpose weights: Wt[qkv][n][k] --------------------
__global__ void cvt_w_kernel(const float* __restrict__ Wq, const float* __restrict__ Wk,
                             const float* __restrict__ Wv, u16* __restrict__ Wt) {
  int idx = blockIdx.x * 256 + threadIdx.x;
  int m = blockIdx.y;
  const float* W = (m == 0) ? Wq : (m == 1) ? Wk : Wv;
  int k = idx / DM, n = idx - k * DM;
  Wt[(size_t)m * DM * DM + (size_t)n * DM + k] = f2bf(W[idx]);
}

// ---- kernel 3: fused QKV GEMM (bf16 MFMA, 256x256 tile, BK=32) ------------
// v5: counted-vmcnt deep pipeline (T4 proper; m218 lesson: 8-phase-with-
// drain0 ~ 1-phase). 512 threads = 8 waves (2M x 4N), wave output 128x64.
// 4 LDS buffers (128KB), prefetch depth 3 K-tiles, 4 stage-loads/K-tile/wave
// (A at s0, B at s1). Per K-tile 2 sub-phases of 16 MFMA:
//   s0: ds_read A0-3,B0-3 | stageA(kt+3) | bar | MFMA | bar
//   s1: ds_read A4-7      | stageB(kt+3) | vmcnt(8) | bar | MFMA | bar
// vmcnt(8) leaves the 8 newer loads in flight and guarantees buf[kt+1]
// (issued 6 phases earlier) has landed; never drains to 0 until the tail
// (kt=21:4, kt=22:0). WAR: buffer reads are reg-consumed before the phase's
// closing barrier; overwrite issues >=1 barrier later. Accumulation order
// per acc[i][j] identical to v4 -> bit-identical output.
__global__ __launch_bounds__(512, 2)
void qkv_gemm_kernel(const u16* __restrict__ Xb, const u16* __restrict__ Wt,
                     const float* __restrict__ bq, const float* __restrict__ bk,
                     const float* __restrict__ bv,
                     u16* __restrict__ Qw, u16* __restrict__ Kw, u16* __restrict__ Vw) {
  // per buffer: 16 entries (16 rows x 32 k) x 64 lanes x 16B = 16KB
  __shared__ alignas(16) u16 As[4][16 * 512];
  __shared__ alignas(16) u16 Bs[4][16 * 512];

  const int tid = threadIdx.x;
  const int lane = tid & 63;
  const int wid = tid >> 6;          // 0..7
  const int wm = wid >> 2, wn = wid & 3;
  const int l15 = lane & 15, lq = lane >> 4;

  // XCD swizzle: 720 blocks = 8 XCDs x 90; 9 consumers (3 nt x 3 qkv) of
  // each 384KB A-slab adjacent on one XCD (Wt 3.5MB ~ L2-resident).
  const int flat = (blockIdx.z * 3 + blockIdx.y) * 80 + blockIdx.x;
  const int xcd = flat & 7;
  const int j8 = flat >> 3;          // 0..89
  const int xi = j8 / 9;             // 0..9
  const int yz = j8 - xi * 9;        // 0..8
  const int mt = xi * 8 + xcd;       // 0..79
  const int nt = yz % 3;
  const int qkv = yz / 3;

  const u16* Wm = Wt + (size_t)qkv * DM * DM;
  const float* bias = (qkv == 0) ? bq : (qkv == 1) ? bk : bv;

  // staging source pointers: wave stages A entries wid*2, wid*2+1; B same
  const u16* gA[2];
  const u16* gB[2];
#pragma unroll
  for (int s = 0; s < 2; ++s) {
    const int e = wid * 2 + s;       // 0..15
    int r = mt * 256 + e * 16 + l15;
    int br = r / SP;
    int tr = r - br * SP;
    if (tr >= SEQ) tr = SEQ - 1;     // clamp padded rows (finite garbage)
    gA[s] = Xb + (size_t)(br * SEQ + tr) * DM + lq * 8;
    gB[s] = Wm + (size_t)(nt * 256 + e * 16 + l15) * DM + lq * 8;
  }

  f32x4 acc[8][4];
#pragma unroll
  for (int i = 0; i < 8; ++i)
#pragma unroll
    for (int j = 0; j < 4; ++j)
#pragma unroll
      for (int r = 0; r < 4; ++r) acc[i][j][r] = 0.0f;

  auto stageA = [&](int buf, int kt) {
    g2l16(gA[0] + kt * 32, &As[buf][(wid * 2 + 0) * 512]);
    g2l16(gA[1] + kt * 32, &As[buf][(wid * 2 + 1) * 512]);
  };
  auto stageB = [&](int buf, int kt) {
    g2l16(gB[0] + kt * 32, &Bs[buf][(wid * 2 + 0) * 512]);
    g2l16(gB[1] + kt * 32, &Bs[buf][(wid * 2 + 1) * 512]);
  };

  // prologue: K-tiles 0..2 staged (12 loads/wave); guarantee buf0 only
  stageA(0, 0); stageB(0, 0);
  stageA(1, 1); stageB(1, 1);
  stageA(2, 2); stageB(2, 2);
  asm volatile("s_waitcnt vmcnt(8)" ::: "memory");  // buf0 landed; 1,2 in flight
  __builtin_amdgcn_s_barrier();

  const int NKT = DM / 32;  // 24
  for (int kt = 0; kt < NKT; ++kt) {
    const int buf = kt & 3;
    const int nbuf = (kt + 3) & 3;
    const bool more = (kt + 3 < NKT);  // kt <= 20
    bf16x8 a03[4], bf4[4], a47[4];

    // ---- s0: read A0-3 + B0-3 (buf guaranteed by prev s1); stage next A ----
#pragma unroll
    for (int i = 0; i < 4; ++i)
      a03[i] = *reinterpret_cast<const bf16x8*>(&As[buf][((wm * 8 + i) * 64 + lane) * 8]);
#pragma unroll
    for (int j = 0; j < 4; ++j)
      bf4[j] = *reinterpret_cast<const bf16x8*>(&Bs[buf][((wn * 4 + j) * 64 + lane) * 8]);
    if (more) stageA(nbuf, kt + 3);
    __builtin_amdgcn_s_barrier();
    __builtin_amdgcn_s_setprio(1);
#pragma unroll
    for (int i = 0; i < 4; ++i)
#pragma unroll
      for (int j = 0; j < 4; ++j)
        acc[i][j] = __builtin_amdgcn_mfma_f32_16x16x32_bf16(a03[i], bf4[j], acc[i][j], 0, 0, 0);
    __builtin_amdgcn_s_setprio(0);
    __builtin_amdgcn_s_barrier();

    // ---- s1: read A4-7; stage next B; counted wait for buf[kt+1] ----
#pragma unroll
    for (int i = 0; i < 4; ++i)
      a47[i] = *reinterpret_cast<const bf16x8*>(&As[buf][((wm * 8 + 4 + i) * 64 + lane) * 8]);
    if (more) stageB(nbuf, kt + 3);
    if (kt <= NKT - 4) {
      asm volatile("s_waitcnt vmcnt(8)" ::: "memory");   // buf[kt+1] landed, 8 in flight
    } else if (kt == NKT - 3) {
      asm volatile("s_waitcnt vmcnt(4)" ::: "memory");   // tail decay
    } else if (kt == NKT - 2) {
      asm volatile("s_waitcnt vmcnt(0)" ::: "memory");
    }
    __builtin_amdgcn_s_barrier();
    __builtin_amdgcn_s_setprio(1);
#pragma unroll
    for (int i = 0; i < 4; ++i)
#pragma unroll
      for (int j = 0; j < 4; ++j)
        acc[4 + i][j] = __builtin_amdgcn_mfma_f32_16x16x32_bf16(a47[i], bf4[j], acc[4 + i][j], 0, 0, 0);
    __builtin_amdgcn_s_setprio(0);
    __builtin_amdgcn_s_barrier();
  }

  const float sfold = 0.18033688011112042f;  // (1/sqrt(64)) * log2(e)
#pragma unroll
  for (int j = 0; j < 4; ++j) {
    const int col = nt * 256 + wn * 64 + j * 16 + l15;
    const int h = col >> 6;
    const int d = col & 63;
    const float bb = bias[col];
#pragma unroll
    for (int i = 0; i < 8; ++i) {
      const int rg = mt * 256 + wm * 128 + i * 16 + lq * 4;
      const int br = rg / SP;
      const int tr = rg - br * SP;   // 640%4==0 -> tr..tr+3 same batch
      if (qkv == 2) {
        float v0 = acc[i][j][0] + bb, v1 = acc[i][j][1] + bb;
        float v2 = acc[i][j][2] + bb, v3 = acc[i][j][3] + bb;
        u32x2 p;
        p[0] = (unsigned)f2bf(v0) | ((unsigned)f2bf(v1) << 16);
        p[1] = (unsigned)f2bf(v2) | ((unsigned)f2bf(v3) << 16);
        size_t o = ((size_t)(br * NH + h) * DH + d) * SP + tr;
        *reinterpret_cast<u32x2*>(Vw + o) = p;
      } else {
        u16* dst = ((qkv == 0) ? Qw : Kw) + ((size_t)(br * NH + h) * SP + tr) * DH + d;
#pragma unroll
        for (int r = 0; r < 4; ++r) {
          float v = acc[i][j][r] + bb;
          if (qkv == 0) v *= sfold;
          dst[r * DH] = f2bf(v);
        }
      }
    }
  }
}

// ---- kernel 4: flash attention v3 -----------------------------------------
// Block = 4 waves = 128 queries (wave owns 32 = 2 q-tiles of 16).
// Per 64-key chunk: K staged via global_load_lds (fragment-ordered 16B/lane),
// V staged via VGPR->ds_write (fragment-ordered 8B/lane), double-buffered,
// one barrier per chunk (m97 structure). S^T = K·Q^T keeps softmax in-lane;
// P stays in-lane as the K=16 PV B-frag (O^T = Vt·P^T). Zero shuffles.
// XCD swizzle (5 q-blocks sharing one head's 160KB K/V -> same XCD L2)
// + s_setprio(1) around MFMA clusters (T5).
#if __has_builtin(__builtin_amdgcn_mfma_f32_16x16x16bf16_1k)
#define MFMA16(a, b, c) __builtin_amdgcn_mfma_f32_16x16x16bf16_1k(a, b, c, 0, 0, 0)
#define HAVE_MFMA16 1
#elif __has_builtin(__builtin_amdgcn_mfma_f32_16x16x16_bf16)
#define MFMA16(a, b, c) __builtin_amdgcn_mfma_f32_16x16x16_bf16(a, b, c, 0, 0, 0)
#define HAVE_MFMA16 1
#else
#define HAVE_MFMA16 0
#endif

__global__ __launch_bounds__(256)
void attn_kernel(const u16* __restrict__ Qw, const u16* __restrict__ Kw,
                 const u16* __restrict__ Vw, float* __restrict__ out) {
  // Kc: 8 entries (t,half) x 64 lanes x 16B = 8KB per buffer
  // Vc: 16 entries (dt,t)  x 64 lanes x  8B = 8KB per buffer
  __shared__ alignas(16) u16 Kc[2][8 * 64 * 8];
  __shared__ alignas(16) u16 Vc[2][16 * 64 * 4];

  const int tid = threadIdx.x;
  const int lane = tid & 63;
  const int wid = tid >> 6;
  const int l15 = lane & 15, lq = lane >> 4;

  // XCD-aware decode: grid (5, 384) -> flat 0..1919; each XCD gets a
  // contiguous range of 240 works = 48 complete (b,h) K/V groups.
  const int flat = blockIdx.y * 5 + blockIdx.x;
  const int w = (flat & 7) * 240 + (flat >> 3);
  const int qx = w % 5;
  const int bh = w / 5;
  const int b = bh / NH;
  const int h = bh - b * NH;
  const int q0 = qx * 128 + wid * 32;  // wave: queries q0..q0+31

  const u16* Qb = Qw + (size_t)bh * SP * DH;
  const u16* Kb = Kw + (size_t)bh * SP * DH;
  const u16* Vb = Vw + (size_t)bh * DH * SP;

  // Q B-frags: [qt][half], B[n=q=l15][k=half*32+lq*8+j]
  bf16x8 qf[2][2];
#pragma unroll
  for (int qt = 0; qt < 2; ++qt)
#pragma unroll
    for (int hf = 0; hf < 2; ++hf)
      qf[qt][hf] = *reinterpret_cast<const bf16x8*>(
          &Qb[(q0 + qt * 16 + l15) * DH + hf * 32 + lq * 8]);

  // staging source addresses (chunk-invariant parts)
  // K: wave stages entries e=2*wid+half: K[c0+wid*16+l15][half*32+lq*8..+8]
  const u16* gK = Kb + (size_t)(wid * 16 + l15) * DH + lq * 8;
  // V: wave stages entries e=4*wid+t: Vt[wid*16+l15][c0+t*16+lq*4..+4]
  const u16* gV = Vb + (size_t)(wid * 16 + l15) * SP + lq * 4;

  float mrow[2] = {-__builtin_inff(), -__builtin_inff()};
  float lrow[2] = {0.0f, 0.0f};
  f32x4 acc[2][4];  // [qt][dt]; d = dt*16+lq*4+r, q = q0+qt*16+l15
#pragma unroll
  for (int qt = 0; qt < 2; ++qt)
#pragma unroll
    for (int dt = 0; dt < 4; ++dt)
#pragma unroll
      for (int r = 0; r < 4; ++r) acc[qt][dt][r] = 0.0f;

  // ---- prologue: stage chunk 0 into buffer 0 ----
  g2l16(gK, &Kc[0][(wid * 2 + 0) * 512]);
  g2l16(gK + 32, &Kc[0][(wid * 2 + 1) * 512]);
  {
    u32x2 v[4];
#pragma unroll
    for (int t = 0; t < 4; ++t)
      v[t] = *reinterpret_cast<const u32x2*>(gV + t * 16);
#pragma unroll
    for (int t = 0; t < 4; ++t)
      *reinterpret_cast<u32x2*>(&Vc[0][((wid * 4 + t) * 64 + lane) * 4]) = v[t];
  }
  __syncthreads();

  for (int c = 0; c < NC; ++c) {
    const int cur = c & 1;
    const int c0 = c * 64;
    // ---- prefetch chunk c+1 (async; drained by end-of-loop barrier) ----
    u32x2 vn[4];
    if (c + 1 < NC) {
      const u16* gKn = gK + (size_t)(c0 + 64) * DH;
      g2l16(gKn, &Kc[cur ^ 1][(wid * 2 + 0) * 512]);
      g2l16(gKn + 32, &Kc[cur ^ 1][(wid * 2 + 1) * 512]);
#pragma unroll
      for (int t = 0; t < 4; ++t)
        vn[t] = *reinterpret_cast<const u32x2*>(gV + (c0 + 64) + t * 16);
    }

    // ---- S^T = K·Q^T from LDS K ----
    f32x4 s[2][4];
    __builtin_amdgcn_s_setprio(1);
#pragma unroll
    for (int t = 0; t < 4; ++t) {
      bf16x8 kf0 = *reinterpret_cast<const bf16x8*>(&Kc[cur][((t * 2 + 0) * 64 + lane) * 8]);
      bf16x8 kf1 = *reinterpret_cast<const bf16x8*>(&Kc[cur][((t * 2 + 1) * 64 + lane) * 8]);
#pragma unroll
      for (int qt = 0; qt < 2; ++qt) {
        f32x4 z;
#pragma unroll
        for (int r = 0; r < 4; ++r) z[r] = 0.0f;
        z = __builtin_amdgcn_mfma_f32_16x16x32_bf16(kf0, qf[qt][0], z, 0, 0, 0);
        z = __builtin_amdgcn_mfma_f32_16x16x32_bf16(kf1, qf[qt][1], z, 0, 0, 0);
        s[qt][t] = z;
      }
    }
    __builtin_amdgcn_s_setprio(0);
    // ---- mask padded keys (uniform branch, last chunk only) ----
    if (c0 + 64 > SEQ) {
#pragma unroll
      for (int qt = 0; qt < 2; ++qt)
#pragma unroll
        for (int t = 0; t < 4; ++t)
#pragma unroll
          for (int r = 0; r < 4; ++r) {
            int key = c0 + t * 16 + lq * 4 + r;
            s[qt][t][r] = (key < SEQ) ? s[qt][t][r] : -__builtin_inff();
          }
    }
    // ---- online softmax (in-lane over 16 + shfl 16,32) ----
    float alpha[2];
    unsigned int pku[2][4][2];
#pragma unroll
    for (int qt = 0; qt < 2; ++qt) {
      float mx = s[qt][0][0];
#pragma unroll
      for (int t = 0; t < 4; ++t)
#pragma unroll
        for (int r = 0; r < 4; ++r) mx = fmaxf(mx, s[qt][t][r]);
      mx = fmaxf(mx, __shfl_xor(mx, 16));
      mx = fmaxf(mx, __shfl_xor(mx, 32));
      float mn = fmaxf(mrow[qt], mx);
      alpha[qt] = __builtin_amdgcn_exp2f(mrow[qt] - mn);
      mrow[qt] = mn;
      float sm = 0.0f;
#pragma unroll
      for (int t = 0; t < 4; ++t) {
        float p0 = __builtin_amdgcn_exp2f(s[qt][t][0] - mn);
        float p1 = __builtin_amdgcn_exp2f(s[qt][t][1] - mn);
        float p2 = __builtin_amdgcn_exp2f(s[qt][t][2] - mn);
        float p3 = __builtin_amdgcn_exp2f(s[qt][t][3] - mn);
        sm += (p0 + p1) + (p2 + p3);
        pku[qt][t][0] = pack_bf2(p0, p1);
        pku[qt][t][1] = pack_bf2(p2, p3);
      }
      sm += __shfl_xor(sm, 16);
      sm += __shfl_xor(sm, 32);
      lrow[qt] = lrow[qt] * alpha[qt] + sm;
    }

#if HAVE_MFMA16
    // ---- PV: O^T = Vt·P^T (K=16 MFMA; vf shared across q-tiles) ----
    __builtin_amdgcn_s_setprio(1);
#pragma unroll
    for (int dt = 0; dt < 4; ++dt) {
      bf16x4 vf[4];
#pragma unroll
      for (int t = 0; t < 4; ++t)
        vf[t] = *reinterpret_cast<const bf16x4*>(&Vc[cur][((dt * 4 + t) * 64 + lane) * 4]);
#pragma unroll
      for (int qt = 0; qt < 2; ++qt) {
        f32x4 a = acc[qt][dt];
#pragma unroll
        for (int r = 0; r < 4; ++r) a[r] *= alpha[qt];
#pragma unroll
        for (int t = 0; t < 4; ++t) {
          bf16x4 pf = __builtin_bit_cast(bf16x4, u32x2{pku[qt][t][0], pku[qt][t][1]});
          a = MFMA16(vf[t], pf, a);
        }
        acc[qt][dt] = a;
      }
    }
    __builtin_amdgcn_s_setprio(0);
#else
    // ---- fallback: K=32 MFMA, B-frag via bpermute (v2-verified pattern) ----
#pragma unroll
    for (int qt = 0; qt < 2; ++qt) {
      unsigned int bfrag[2][4];
#pragma unroll
      for (int hh = 0; hh < 2; ++hh)
#pragma unroll
        for (int w2 = 0; w2 < 4; ++w2) {
          int srcl = l15 + 16 * (2 * (lq & 1) + (w2 >> 1));
          unsigned int lo = (unsigned int)__shfl((int)pku[qt][2 * hh][w2 & 1], srcl);
          unsigned int hi = (unsigned int)__shfl((int)pku[qt][2 * hh + 1][w2 & 1], srcl);
          bfrag[hh][w2] = (lq < 2) ? lo : hi;
        }
#pragma unroll
      for (int dt = 0; dt < 4; ++dt) {
        f32x4 a = acc[qt][dt];
#pragma unroll
        for (int r = 0; r < 4; ++r) a[r] *= alpha[qt];
#pragma unroll
        for (int hh = 0; hh < 2; ++hh) {
          u32x2 w0 = *reinterpret_cast<const u32x2*>(&Vc[cur][((dt * 4 + 2 * hh) * 64 + lane) * 4]);
          u32x2 w1 = *reinterpret_cast<const u32x2*>(&Vc[cur][((dt * 4 + 2 * hh + 1) * 64 + lane) * 4]);
          u32x4 vw = {w0[0], w0[1], w1[0], w1[1]};
          u32x4 pw = {bfrag[hh][0], bfrag[hh][1], bfrag[hh][2], bfrag[hh][3]};
          a = __builtin_amdgcn_mfma_f32_16x16x32_bf16(
              __builtin_bit_cast(bf16x8, vw), __builtin_bit_cast(bf16x8, pw), a, 0, 0, 0);
        }
        acc[qt][dt] = a;
      }
    }
#endif

    // ---- write prefetched V into the other buffer, then barrier ----
    if (c + 1 < NC) {
#pragma unroll
      for (int t = 0; t < 4; ++t)
        *reinterpret_cast<u32x2*>(&Vc[cur ^ 1][((wid * 4 + t) * 64 + lane) * 4]) = vn[t];
    }
    __syncthreads();
  }

  // ---- epilogue: direct stores (lane holds 4 consecutive d -> 16B store) ----
#pragma unroll
  for (int qt = 0; qt < 2; ++qt) {
    int q = q0 + qt * 16 + l15;
    if (q < SEQ) {
      float rl = 1.0f / lrow[qt];
      float* orow = out + ((size_t)b * SEQ + q) * DM + h * DH;
#pragma unroll
      for (int dt = 0; dt < 4; ++dt) {
        f32x4 v = acc[qt][dt];
#pragma unroll
        for (int r = 0; r < 4; ++r) v[r] *= rl;
        *reinterpret_cast<f32x4*>(&orow[dt * 16 + lq * 4]) = v;
      }
    }
  }
}

extern "C" void kernel_launch(void* const* d_in, const int* in_sizes, int n_in,
                              void* d_out, int out_size, void* d_ws, size_t ws_size,
                              hipStream_t stream) {
  (void)in_sizes; (void)n_in; (void)out_size; (void)ws_size;
  const float* X  = (const float*)d_in[0];
  const float* Wq = (const float*)d_in[1];
  const float* bq = (const float*)d_in[2];
  const float* Wk = (const float*)d_in[3];
  const float* bk = (const float*)d_in[4];
  const float* Wv = (const float*)d_in[5];
  const float* bv = (const float*)d_in[6];
  float* out = (float*)d_out;

  char* ws = (char*)d_ws;
  u16* Xb = (u16*)ws;
  u16* Wt = (u16*)(ws + 28366848);
  u16* Qw = (u16*)(ws + 28366848 + 3538944);
  u16* Kw = Qw + (size_t)NB * NH * SP * DH;
  u16* Vw = Kw + (size_t)NB * NH * SP * DH;

  cvt_x_kernel<<<dim3(13848), 256, 0, stream>>>(X, Xb, 3545088);
  cvt_w_kernel<<<dim3(2304, 3), 256, 0, stream>>>(Wq, Wk, Wv, Wt);
  qkv_gemm_kernel<<<dim3(80, 3, 3), 512, 0, stream>>>(Xb, Wt, bq, bk, bv, Qw, Kw, Vw);
  attn_kernel<<<dim3(5, NB * NH), 256, 0, stream>>>(Qw, Kw, Vw, out);
}

// Round 5
// 307.072 us; speedup vs baseline: 1.2338x; 1.0637x over previous
//
#include <hip/hip_runtime.h>

// B=32, S=577, D=768, H=12, Dh=64. fp32 in/out, bf16 MFMA compute.
#define NB 32
#define SEQ 577
#define SP 640      // padded seq (5*128, 10*64)
#define DM 768
#define NH 12
#define DH 64
#define NC 10       // key chunks of 64

typedef __attribute__((ext_vector_type(8))) short bf16x8;   // K=32 MFMA A/B frag
typedef __attribute__((ext_vector_type(4))) short bf16x4;   // K=16 MFMA A/B frag
typedef __attribute__((ext_vector_type(4))) float f32x4;
typedef __attribute__((ext_vector_type(2))) unsigned int u32x2;
typedef __attribute__((ext_vector_type(4))) unsigned int u32x4;
typedef unsigned short u16;

__device__ __forceinline__ u16 f2bf(float f) {  // RNE float->bf16
  unsigned int u = __builtin_bit_cast(unsigned int, f);
  u += 0x7fffu + ((u >> 16) & 1u);
  return (u16)(u >> 16);
}

// pack two fp32 -> bf16 pair (round-half-up) in one v_perm
__device__ __forceinline__ unsigned int pack_bf2(float a, float b) {
  unsigned int ua = __builtin_bit_cast(unsigned int, a) + 0x8000u;
  unsigned int ub = __builtin_bit_cast(unsigned int, b) + 0x8000u;
  return __builtin_amdgcn_perm(ub, ua, 0x07060302u);  // lo16=bf(a), hi16=bf(b)
}

__device__ __forceinline__ void g2l16(const void* g, void* lds) {
  __builtin_amdgcn_global_load_lds(
      (const __attribute__((address_space(1))) void*)g,
      (__attribute__((address_space(3))) void*)lds, 16, 0, 0);
}

// ---- kernel 1: fp32 -> bf16 cast of hidden_states -------------------------
__global__ void cvt_x_kernel(const float* __restrict__ X, u16* __restrict__ Xb, int n4) {
  int i = blockIdx.x * 256 + threadIdx.x;
  if (i >= n4) return;
  f32x4 v = *reinterpret_cast<const f32x4*>(X + (size_t)i * 4);
  u32x2 p;
  p[0] = (unsigned)f2bf(v[0]) | ((unsigned)f2bf(v[1]) << 16);
  p[1] = (unsigned)f2bf(v[2]) | ((unsigned)f2bf(v[3]) << 16);
  *reinterpret_cast<u32x2*>(Xb + (size_t)i * 4) = p;
}

// ---- kernel 2: cast + transpose weights via LDS tile ----------------------
// v6: 64x64 LDS-tiled transpose. Coalesced f32x4 reads, LDS [n][k] (stride
// 72 keeps 16B alignment + bank spread), coalesced 16B writes. Replaces the
// fully-scattered 2B global stores (64 lines per wave store) of the old
// version.
__global__ __launch_bounds__(256)
void cvt_w_kernel(const float* __restrict__ Wq, const float* __restrict__ Wk,
                  const float* __restrict__ Wv, u16* __restrict__ Wt) {
  __shared__ u16 ld[64 * 72];
  const int m = blockIdx.z;
  const float* W = (m == 0) ? Wq : (m == 1) ? Wk : Wv;
  const int k0 = blockIdx.y * 64, n0 = blockIdx.x * 64;
  const int tid = threadIdx.x;
  const int kr = tid >> 4, c4 = tid & 15;
#pragma unroll
  for (int p = 0; p < 4; ++p) {
    const int k = p * 16 + kr;
    f32x4 v = *reinterpret_cast<const f32x4*>(&W[(size_t)(k0 + k) * DM + n0 + c4 * 4]);
#pragma unroll
    for (int e = 0; e < 4; ++e) ld[(c4 * 4 + e) * 72 + k] = f2bf(v[e]);
  }
  __syncthreads();
  u16* dst = Wt + (size_t)m * DM * DM;
#pragma unroll
  for (int p = 0; p < 2; ++p) {
    const int s = p * 256 + tid;
    const int n = s >> 3, ch = (s & 7) * 8;
    u32x4 w = *reinterpret_cast<const u32x4*>(&ld[n * 72 + ch]);
    *reinterpret_cast<u32x4*>(&dst[(size_t)(n0 + n) * DM + k0 + ch]) = w;
  }
}

// ---- kernel 3: fused QKV GEMM (bf16 MFMA, 256x256 tile, BK=32) ------------
// v6: = v5 counted-vmcnt deep pipeline (4 LDS bufs, depth-3 prefetch,
// vmcnt(8) steady state, 2 sub-phases of 16 MFMA per K-tile) PLUS:
//  - one dispatch per qkv (visibility + per-qkv L2 residency); grid (80,3).
//  - LDS-transpose epilogue: acc -> sh tile ([row][col] for Q/K, [col][row]
//    for V, stride 264 = 16B-aligned rows), barrier, then 16 passes of
//    fully-coalesced 16B stores. Kills the 2B/8B scattered stores that
//    inflated WRITE_SIZE 165 MB vs 94 MB ideal.
// sh (132KB) aliases the pipeline buffers (128KB); epilogue starts after the
// K-loop's final barrier so all reads have drained.
__global__ __launch_bounds__(512, 2)
void qkv_gemm_kernel(const u16* __restrict__ Xb, const u16* __restrict__ Wt,
                     const float* __restrict__ bq, const float* __restrict__ bk,
                     const float* __restrict__ bv,
                     u16* __restrict__ Qw, u16* __restrict__ Kw, u16* __restrict__ Vw,
                     const int qkv) {
  __shared__ alignas(16) u16 sh[256 * 264];  // 132KB; pipeline uses first 128KB

  const int tid = threadIdx.x;
  const int lane = tid & 63;
  const int wid = tid >> 6;          // 0..7
  const int wm = wid >> 2, wn = wid & 3;
  const int l15 = lane & 15, lq = lane >> 4;

  // XCD swizzle: 240 blocks = 8 XCDs x 30; 3 nt consumers of each 384KB
  // A-slab adjacent on one XCD (per-dispatch Wt slice 1.2MB L2-resident).
  const int flat = blockIdx.y * 80 + blockIdx.x;  // 0..239
  const int xcd = flat & 7;
  const int j8 = flat >> 3;          // 0..29
  const int xi = j8 / 3;             // 0..9
  const int nt = j8 - xi * 3;        // 0..2
  const int mt = xi * 8 + xcd;       // 0..79

  const u16* Wm = Wt + (size_t)qkv * DM * DM;
  const float* bias = (qkv == 0) ? bq : (qkv == 1) ? bk : bv;

  // staging source pointers: wave stages A entries wid*2, wid*2+1; B same
  const u16* gA[2];
  const u16* gB[2];
#pragma unroll
  for (int s = 0; s < 2; ++s) {
    const int e = wid * 2 + s;       // 0..15
    int r = mt * 256 + e * 16 + l15;
    int br = r / SP;
    int tr = r - br * SP;
    if (tr >= SEQ) tr = SEQ - 1;     // clamp padded rows (finite garbage)
    gA[s] = Xb + (size_t)(br * SEQ + tr) * DM + lq * 8;
    gB[s] = Wm + (size_t)(nt * 256 + e * 16 + l15) * DM + lq * 8;
  }

  f32x4 acc[8][4];
#pragma unroll
  for (int i = 0; i < 8; ++i)
#pragma unroll
    for (int j = 0; j < 4; ++j)
#pragma unroll
      for (int r = 0; r < 4; ++r) acc[i][j][r] = 0.0f;

  auto stageA = [&](int buf, int kt) {
    g2l16(gA[0] + kt * 32, &sh[buf * 8192 + (wid * 2 + 0) * 512]);
    g2l16(gA[1] + kt * 32, &sh[buf * 8192 + (wid * 2 + 1) * 512]);
  };
  auto stageB = [&](int buf, int kt) {
    g2l16(gB[0] + kt * 32, &sh[32768 + buf * 8192 + (wid * 2 + 0) * 512]);
    g2l16(gB[1] + kt * 32, &sh[32768 + buf * 8192 + (wid * 2 + 1) * 512]);
  };

  // prologue: K-tiles 0..2 staged (12 loads/wave); guarantee buf0 only
  stageA(0, 0); stageB(0, 0);
  stageA(1, 1); stageB(1, 1);
  stageA(2, 2); stageB(2, 2);
  asm volatile("s_waitcnt vmcnt(8)" ::: "memory");  // buf0 landed; 1,2 in flight
  __builtin_amdgcn_s_barrier();

  const int NKT = DM / 32;  // 24
  for (int kt = 0; kt < NKT; ++kt) {
    const int buf = kt & 3;
    const int nbuf = (kt + 3) & 3;
    const bool more = (kt + 3 < NKT);  // kt <= 20
    bf16x8 a03[4], bf4[4], a47[4];

    // ---- s0: read A0-3 + B0-3 (buf guaranteed by prev s1); stage next A ----
#pragma unroll
    for (int i = 0; i < 4; ++i)
      a03[i] = *reinterpret_cast<const bf16x8*>(&sh[buf * 8192 + ((wm * 8 + i) * 64 + lane) * 8]);
#pragma unroll
    for (int j = 0; j < 4; ++j)
      bf4[j] = *reinterpret_cast<const bf16x8*>(&sh[32768 + buf * 8192 + ((wn * 4 + j) * 64 + lane) * 8]);
    if (more) stageA(nbuf, kt + 3);
    __builtin_amdgcn_s_barrier();
    __builtin_amdgcn_s_setprio(1);
#pragma unroll
    for (int i = 0; i < 4; ++i)
#pragma unroll
      for (int j = 0; j < 4; ++j)
        acc[i][j] = __builtin_amdgcn_mfma_f32_16x16x32_bf16(a03[i], bf4[j], acc[i][j], 0, 0, 0);
    __builtin_amdgcn_s_setprio(0);
    __builtin_amdgcn_s_barrier();

    // ---- s1: read A4-7; stage next B; counted wait for buf[kt+1] ----
#pragma unroll
    for (int i = 0; i < 4; ++i)
      a47[i] = *reinterpret_cast<const bf16x8*>(&sh[buf * 8192 + ((wm * 8 + 4 + i) * 64 + lane) * 8]);
    if (more) stageB(nbuf, kt + 3);
    if (kt <= NKT - 4) {
      asm volatile("s_waitcnt vmcnt(8)" ::: "memory");   // buf[kt+1] landed, 8 in flight
    } else if (kt == NKT - 3) {
      asm volatile("s_waitcnt vmcnt(4)" ::: "memory");   // tail decay
    } else if (kt == NKT - 2) {
      asm volatile("s_waitcnt vmcnt(0)" ::: "memory");
    }
    __builtin_amdgcn_s_barrier();
    __builtin_amdgcn_s_setprio(1);
#pragma unroll
    for (int i = 0; i < 4; ++i)
#pragma unroll
      for (int j = 0; j < 4; ++j)
        acc[4 + i][j] = __builtin_amdgcn_mfma_f32_16x16x32_bf16(a47[i], bf4[j], acc[4 + i][j], 0, 0, 0);
    __builtin_amdgcn_s_setprio(0);
    __builtin_amdgcn_s_barrier();
  }

  // ---- epilogue phase 1: acc -> LDS tile (bias/scale/pack applied) ----
  const float sfold = 0.18033688011112042f;  // (1/sqrt(64)) * log2(e)
#pragma unroll
  for (int j = 0; j < 4; ++j) {
    const int col = wn * 64 + j * 16 + l15;          // local col 0..255
    const float bb = bias[nt * 256 + col];
#pragma unroll
    for (int i = 0; i < 8; ++i) {
      const int row = wm * 128 + i * 16 + lq * 4;    // local row 0..252
      if (qkv == 2) {
        // V: [col][row] so tr becomes the contiguous axis on re-read
        unsigned p0 = (unsigned)f2bf(acc[i][j][0] + bb) | ((unsigned)f2bf(acc[i][j][1] + bb) << 16);
        unsigned p1 = (unsigned)f2bf(acc[i][j][2] + bb) | ((unsigned)f2bf(acc[i][j][3] + bb) << 16);
        *reinterpret_cast<u32x2*>(&sh[col * 264 + row]) = u32x2{p0, p1};
      } else {
#pragma unroll
        for (int r = 0; r < 4; ++r) {
          float v = acc[i][j][r] + bb;
          if (qkv == 0) v *= sfold;
          sh[(row + r) * 264 + col] = f2bf(v);
        }
      }
    }
  }
  __builtin_amdgcn_s_barrier();

  // ---- epilogue phase 2: LDS -> global, coalesced 16B stores ----
#pragma unroll
  for (int p = 0; p < 16; ++p) {
    const int slot = p * 512 + tid;      // 0..8191
    const int rr = slot >> 5;            // 0..255
    const int cc = (slot & 31) * 8;      // 0..248
    u32x4 w = *reinterpret_cast<const u32x4*>(&sh[rr * 264 + cc]);
    if (qkv == 2) {
      // rr = local d-col, cc..cc+7 = local rows (8 | 640 -> same batch)
      const int gcol = nt * 256 + rr;
      const int h = gcol >> 6, d = gcol & 63;
      const int rg = mt * 256 + cc;
      const int br = rg / SP, tr = rg - br * SP;
      *reinterpret_cast<u32x4*>(&Vw[((size_t)(br * NH + h) * DH + d) * SP + tr]) = w;
    } else {
      const int rg = mt * 256 + rr;
      const int br = rg / SP, tr = rg - br * SP;
      const int gcol = nt * 256 + cc;
      const int h = gcol >> 6, d = gcol & 63;   // cc%64: 8 cols within one head
      u16* dst = ((qkv == 0) ? Qw : Kw) + ((size_t)(br * NH + h) * SP + tr) * DH + d;
      *reinterpret_cast<u32x4*>(dst) = w;
    }
  }
}

// ---- kernel 4: flash attention v3 -----------------------------------------
// Block = 4 waves = 128 queries (wave owns 32 = 2 q-tiles of 16).
// Per 64-key chunk: K staged via global_load_lds (fragment-ordered 16B/lane),
// V staged via VGPR->ds_write (fragment-ordered 8B/lane), double-buffered,
// one barrier per chunk (m97 structure). S^T = K·Q^T keeps softmax in-lane;
// P stays in-lane as the K=16 PV B-frag (O^T = Vt·P^T). Zero shuffles.
// XCD swizzle (5 q-blocks sharing one head's 160KB K/V -> same XCD L2)
// + s_setprio(1) around MFMA clusters (T5).
#if __has_builtin(__builtin_amdgcn_mfma_f32_16x16x16bf16_1k)
#define MFMA16(a, b, c) __builtin_amdgcn_mfma_f32_16x16x16bf16_1k(a, b, c, 0, 0, 0)
#define HAVE_MFMA16 1
#elif __has_builtin(__builtin_amdgcn_mfma_f32_16x16x16_bf16)
#define MFMA16(a, b, c) __builtin_amdgcn_mfma_f32_16x16x16_bf16(a, b, c, 0, 0, 0)
#define HAVE_MFMA16 1
#else
#define HAVE_MFMA16 0
#endif

__global__ __launch_bounds__(256)
void attn_kernel(const u16* __restrict__ Qw, const u16* __restrict__ Kw,
                 const u16* __restrict__ Vw, float* __restrict__ out) {
  // Kc: 8 entries (t,half) x 64 lanes x 16B = 8KB per buffer
  // Vc: 16 entries (dt,t)  x 64 lanes x  8B = 8KB per buffer
  __shared__ alignas(16) u16 Kc[2][8 * 64 * 8];
  __shared__ alignas(16) u16 Vc[2][16 * 64 * 4];

  const int tid = threadIdx.x;
  const int lane = tid & 63;
  const int wid = tid >> 6;
  const int l15 = lane & 15, lq = lane >> 4;

  // XCD-aware decode: grid (5, 384) -> flat 0..1919; each XCD gets a
  // contiguous range of 240 works = 48 complete (b,h) K/V groups.
  const int flat = blockIdx.y * 5 + blockIdx.x;
  const int w = (flat & 7) * 240 + (flat >> 3);
  const int qx = w % 5;
  const int bh = w / 5;
  const int b = bh / NH;
  const int h = bh - b * NH;
  const int q0 = qx * 128 + wid * 32;  // wave: queries q0..q0+31

  const u16* Qb = Qw + (size_t)bh * SP * DH;
  const u16* Kb = Kw + (size_t)bh * SP * DH;
  const u16* Vb = Vw + (size_t)bh * DH * SP;

  // Q B-frags: [qt][half], B[n=q=l15][k=half*32+lq*8+j]
  bf16x8 qf[2][2];
#pragma unroll
  for (int qt = 0; qt < 2; ++qt)
#pragma unroll
    for (int hf = 0; hf < 2; ++hf)
      qf[qt][hf] = *reinterpret_cast<const bf16x8*>(
          &Qb[(q0 + qt * 16 + l15) * DH + hf * 32 + lq * 8]);

  // staging source addresses (chunk-invariant parts)
  // K: wave stages entries e=2*wid+half: K[c0+wid*16+l15][half*32+lq*8..+8]
  const u16* gK = Kb + (size_t)(wid * 16 + l15) * DH + lq * 8;
  // V: wave stages entries e=4*wid+t: Vt[wid*16+l15][c0+t*16+lq*4..+4]
  const u16* gV = Vb + (size_t)(wid * 16 + l15) * SP + lq * 4;

  float mrow[2] = {-__builtin_inff(), -__builtin_inff()};
  float lrow[2] = {0.0f, 0.0f};
  f32x4 acc[2][4];  // [qt][dt]; d = dt*16+lq*4+r, q = q0+qt*16+l15
#pragma unroll
  for (int qt = 0; qt < 2; ++qt)
#pragma unroll
    for (int dt = 0; dt < 4; ++dt)
#pragma unroll
      for (int r = 0; r < 4; ++r) acc[qt][dt][r] = 0.0f;

  // ---- prologue: stage chunk 0 into buffer 0 ----
  g2l16(gK, &Kc[0][(wid * 2 + 0) * 512]);
  g2l16(gK + 32, &Kc[0][(wid * 2 + 1) * 512]);
  {
    u32x2 v[4];
#pragma unroll
    for (int t = 0; t < 4; ++t)
      v[t] = *reinterpret_cast<const u32x2*>(gV + t * 16);
#pragma unroll
    for (int t = 0; t < 4; ++t)
      *reinterpret_cast<u32x2*>(&Vc[0][((wid * 4 + t) * 64 + lane) * 4]) = v[t];
  }
  __syncthreads();

  for (int c = 0; c < NC; ++c) {
    const int cur = c & 1;
    const int c0 = c * 64;
    // ---- prefetch chunk c+1 (async; drained by end-of-loop barrier) ----
    u32x2 vn[4];
    if (c + 1 < NC) {
      const u16* gKn = gK + (size_t)(c0 + 64) * DH;
      g2l16(gKn, &Kc[cur ^ 1][(wid * 2 + 0) * 512]);
      g2l16(gKn + 32, &Kc[cur ^ 1][(wid * 2 + 1) * 512]);
#pragma unroll
      for (int t = 0; t < 4; ++t)
        vn[t] = *reinterpret_cast<const u32x2*>(gV + (c0 + 64) + t * 16);
    }

    // ---- S^T = K·Q^T from LDS K ----
    f32x4 s[2][4];
    __builtin_amdgcn_s_setprio(1);
#pragma unroll
    for (int t = 0; t < 4; ++t) {
      bf16x8 kf0 = *reinterpret_cast<const bf16x8*>(&Kc[cur][((t * 2 + 0) * 64 + lane) * 8]);
      bf16x8 kf1 = *reinterpret_cast<const bf16x8*>(&Kc[cur][((t * 2 + 1) * 64 + lane) * 8]);
#pragma unroll
      for (int qt = 0; qt < 2; ++qt) {
        f32x4 z;
#pragma unroll
        for (int r = 0; r < 4; ++r) z[r] = 0.0f;
        z = __builtin_amdgcn_mfma_f32_16x16x32_bf16(kf0, qf[qt][0], z, 0, 0, 0);
        z = __builtin_amdgcn_mfma_f32_16x16x32_bf16(kf1, qf[qt][1], z, 0, 0, 0);
        s[qt][t] = z;
      }
    }
    __builtin_amdgcn_s_setprio(0);
    // ---- mask padded keys (uniform branch, last chunk only) ----
    if (c0 + 64 > SEQ) {
#pragma unroll
      for (int qt = 0; qt < 2; ++qt)
#pragma unroll
        for (int t = 0; t < 4; ++t)
#pragma unroll
          for (int r = 0; r < 4; ++r) {
            int key = c0 + t * 16 + lq * 4 + r;
            s[qt][t][r] = (key < SEQ) ? s[qt][t][r] : -__builtin_inff();
          }
    }
    // ---- online softmax (in-lane over 16 + shfl 16,32) ----
    float alpha[2];
    unsigned int pku[2][4][2];
#pragma unroll
    for (int qt = 0; qt < 2; ++qt) {
      float mx = s[qt][0][0];
#pragma unroll
      for (int t = 0; t < 4; ++t)
#pragma unroll
        for (int r = 0; r < 4; ++r) mx = fmaxf(mx, s[qt][t][r]);
      mx = fmaxf(mx, __shfl_xor(mx, 16));
      mx = fmaxf(mx, __shfl_xor(mx, 32));
      float mn = fmaxf(mrow[qt], mx);
      alpha[qt] = __builtin_amdgcn_exp2f(mrow[qt] - mn);
      mrow[qt] = mn;
      float sm = 0.0f;
#pragma unroll
      for (int t = 0; t < 4; ++t) {
        float p0 = __builtin_amdgcn_exp2f(s[qt][t][0] - mn);
        float p1 = __builtin_amdgcn_exp2f(s[qt][t][1] - mn);
        float p2 = __builtin_amdgcn_exp2f(s[qt][t][2] - mn);
        float p3 = __builtin_amdgcn_exp2f(s[qt][t][3] - mn);
        sm += (p0 + p1) + (p2 + p3);
        pku[qt][t][0] = pack_bf2(p0, p1);
        pku[qt][t][1] = pack_bf2(p2, p3);
      }
      sm += __shfl_xor(sm, 16);
      sm += __shfl_xor(sm, 32);
      lrow[qt] = lrow[qt] * alpha[qt] + sm;
    }

#if HAVE_MFMA16
    // ---- PV: O^T = Vt·P^T (K=16 MFMA; vf shared across q-tiles) ----
    __builtin_amdgcn_s_setprio(1);
#pragma unroll
    for (int dt = 0; dt < 4; ++dt) {
      bf16x4 vf[4];
#pragma unroll
      for (int t = 0; t < 4; ++t)
        vf[t] = *reinterpret_cast<const bf16x4*>(&Vc[cur][((dt * 4 + t) * 64 + lane) * 4]);
#pragma unroll
      for (int qt = 0; qt < 2; ++qt) {
        f32x4 a = acc[qt][dt];
#pragma unroll
        for (int r = 0; r < 4; ++r) a[r] *= alpha[qt];
#pragma unroll
        for (int t = 0; t < 4; ++t) {
          bf16x4 pf = __builtin_bit_cast(bf16x4, u32x2{pku[qt][t][0], pku[qt][t][1]});
          a = MFMA16(vf[t], pf, a);
        }
        acc[qt][dt] = a;
      }
    }
    __builtin_amdgcn_s_setprio(0);
#else
    // ---- fallback: K=32 MFMA, B-frag via bpermute (v2-verified pattern) ----
#pragma unroll
    for (int qt = 0; qt < 2; ++qt) {
      unsigned int bfrag[2][4];
#pragma unroll
      for (int hh = 0; hh < 2; ++hh)
#pragma unroll
        for (int w2 = 0; w2 < 4; ++w2) {
          int srcl = l15 + 16 * (2 * (lq & 1) + (w2 >> 1));
          unsigned int lo = (unsigned int)__shfl((int)pku[qt][2 * hh][w2 & 1], srcl);
          unsigned int hi = (unsigned int)__shfl((int)pku[qt][2 * hh + 1][w2 & 1], srcl);
          bfrag[hh][w2] = (lq < 2) ? lo : hi;
        }
#pragma unroll
      for (int dt = 0; dt < 4; ++dt) {
        f32x4 a = acc[qt][dt];
#pragma unroll
        for (int r = 0; r < 4; ++r) a[r] *= alpha[qt];
#pragma unroll
        for (int hh = 0; hh < 2; ++hh) {
          u32x2 w0 = *reinterpret_cast<const u32x2*>(&Vc[cur][((dt * 4 + 2 * hh) * 64 + lane) * 4]);
          u32x2 w1 = *reinterpret_cast<const u32x2*>(&Vc[cur][((dt * 4 + 2 * hh + 1) * 64 + lane) * 4]);
          u32x4 vw = {w0[0], w0[1], w1[0], w1[1]};
          u32x4 pw = {bfrag[hh][0], bfrag[hh][1], bfrag[hh][2], bfrag[hh][3]};
          a = __builtin_amdgcn_mfma_f32_16x16x32_bf16(
              __builtin_bit_cast(bf16x8, vw), __builtin_bit_cast(bf16x8, pw), a, 0, 0, 0);
        }
        acc[qt][dt] = a;
      }
    }
#endif

    // ---- write prefetched V into the other buffer, then barrier ----
    if (c + 1 < NC) {
#pragma unroll
      for (int t = 0; t < 4; ++t)
        *reinterpret_cast<u32x2*>(&Vc[cur ^ 1][((wid * 4 + t) * 64 + lane) * 4]) = vn[t];
    }
    __syncthreads();
  }

  // ---- epilogue: direct stores (lane holds 4 consecutive d -> 16B store) ----
#pragma unroll
  for (int qt = 0; qt < 2; ++qt) {
    int q = q0 + qt * 16 + l15;
    if (q < SEQ) {
      float rl = 1.0f / lrow[qt];
      float* orow = out + ((size_t)b * SEQ + q) * DM + h * DH;
#pragma unroll
      for (int dt = 0; dt < 4; ++dt) {
        f32x4 v = acc[qt][dt];
#pragma unroll
        for (int r = 0; r < 4; ++r) v[r] *= rl;
        *reinterpret_cast<f32x4*>(&orow[dt * 16 + lq * 4]) = v;
      }
    }
  }
}

extern "C" void kernel_launch(void* const* d_in, const int* in_sizes, int n_in,
                              void* d_out, int out_size, void* d_ws, size_t ws_size,
                              hipStream_t stream) {
  (void)in_sizes; (void)n_in; (void)out_size; (void)ws_size;
  const float* X  = (const float*)d_in[0];
  const float* Wq = (const float*)d_in[1];
  const float* bq = (const float*)d_in[2];
  const float* Wk = (const float*)d_in[3];
  const float* bk = (const float*)d_in[4];
  const float* Wv = (const float*)d_in[5];
  const float* bv = (const float*)d_in[6];
  float* out = (float*)d_out;

  char* ws = (char*)d_ws;
  u16* Xb = (u16*)ws;
  u16* Wt = (u16*)(ws + 28366848);
  u16* Qw = (u16*)(ws + 28366848 + 3538944);
  u16* Kw = Qw + (size_t)NB * NH * SP * DH;
  u16* Vw = Kw + (size_t)NB * NH * SP * DH;

  cvt_x_kernel<<<dim3(13848), 256, 0, stream>>>(X, Xb, 3545088);
  cvt_w_kernel<<<dim3(12, 12, 3), 256, 0, stream>>>(Wq, Wk, Wv, Wt);
  qkv_gemm_kernel<<<dim3(80, 3), 512, 0, stream>>>(Xb, Wt, bq, bk, bv, Qw, Kw, Vw, 0);
  qkv_gemm_kernel<<<dim3(80, 3), 512, 0, stream>>>(Xb, Wt, bq, bk, bv, Qw, Kw, Vw, 1);
  qkv_gemm_kernel<<<dim3(80, 3), 512, 0, stream>>>(Xb, Wt, bq, bk, bv, Qw, Kw, Vw, 2);
  attn_kernel<<<dim3(5, NB * NH), 256, 0, stream>>>(Qw, Kw, Vw, out);
}